// Round 20
// baseline (407.972 us; speedup 1.0000x reference)
//
#include <hip/hip_runtime.h>
#include <math.h>

#ifndef M_PI
#define M_PI 3.14159265358979323846
#endif

#define TBL_MAGIC 0x5EED5EEDCAFEF00EULL

__device__ const int c_off2[11] = {0,1,10,35,84,165,286,455,680,969,1330};
__device__ const int c_offH[11] = {0,1,7,22,50,95,161,252,372,525,715};
__device__ const int c_T[17] = {0,1,3,6,10,15,21,28,36,45,55,66,78,91,105,120,136};

__device__ constexpr float CS32[32] = {
  1.0f, 0.98078528f, 0.92387953f, 0.83146961f, 0.70710678f, 0.55557023f, 0.38268343f, 0.19509032f,
  0.0f,-0.19509032f,-0.38268343f,-0.55557023f,-0.70710678f,-0.83146961f,-0.92387953f,-0.98078528f,
 -1.0f,-0.98078528f,-0.92387953f,-0.83146961f,-0.70710678f,-0.55557023f,-0.38268343f,-0.19509032f,
  0.0f, 0.19509032f, 0.38268343f, 0.55557023f, 0.70710678f, 0.83146961f, 0.92387953f, 0.98078528f};
__device__ constexpr float SN32[32] = {
  0.0f, 0.19509032f, 0.38268343f, 0.55557023f, 0.70710678f, 0.83146961f, 0.92387953f, 0.98078528f,
  1.0f, 0.98078528f, 0.92387953f, 0.83146961f, 0.70710678f, 0.55557023f, 0.38268343f, 0.19509032f,
  0.0f,-0.19509032f,-0.38268343f,-0.55557023f,-0.70710678f,-0.83146961f,-0.92387953f,-0.98078528f,
 -1.0f,-0.98078528f,-0.92387953f,-0.83146961f,-0.70710678f,-0.55557023f,-0.38268343f,-0.19509032f};

__device__ __forceinline__ int l_from_sq(int off){ int l=0; while((l+1)*(l+1)<=off) l++; return l; }
__device__ __forceinline__ int l_from_offH(int off){ int l=0; while(c_offH[l+1]<=off) l++; return l; }
__device__ __forceinline__ int l_from_T(int c){ int l=0; while(c_T[l+1]<=c) l++; return l; }

// ---------------- k_dq: fused Wigner Delta (blocks 0-15) + qw/phase tables (block 16) ----------------
__global__ void k_dq(double* Dd, float* Df, float* qw30, float* qw16, float* qw10,
                     float2* ph32, float2* ph20, float2* ph60,
                     const unsigned long long* __restrict__ tflag){
  if (tflag[0]==TBL_MAGIC) return;
  if (blockIdx.x==16){
    int t=threadIdx.x;
    if (t<60){
      double beta=M_PI*(2*t+1)/120.0, s=0.0;
      for (int j=0;j<30;j++) s += sin((double)(2*t+1)*(2*j+1)*M_PI/120.0)/(double)(2*j+1);
      qw30[t]=(float)((2.0/30.0)*sin(beta)*s);
      double a=2.0*M_PI*t/60.0; ph60[t]=make_float2((float)cos(a),(float)sin(a));
    }
    if (t<32){
      double beta=M_PI*(2*t+1)/64.0, s=0.0;
      for (int j=0;j<16;j++) s += sin((double)(2*t+1)*(2*j+1)*M_PI/64.0)/(double)(2*j+1);
      qw16[t]=(float)((2.0/16.0)*sin(beta)*s);
      double a=2.0*M_PI*t/32.0; ph32[t]=make_float2((float)cos(a),(float)sin(a));
    }
    if (t<20){
      double beta=M_PI*(2*t+1)/40.0, s=0.0;
      for (int j=0;j<10;j++) s += sin((double)(2*t+1)*(2*j+1)*M_PI/40.0)/(double)(2*j+1);
      qw10[t]=(float)((2.0/10.0)*sin(beta)*s);
      double a=2.0*M_PI*t/20.0; ph20[t]=make_float2((float)cos(a),(float)sin(a));
    }
    return;
  }
  int l = blockIdx.x; int n = 2*l+1; int n2=n*n;
  __shared__ double A[961], T[961], Tm[961];
  for (int idx=threadIdx.x; idx<n2; idx+=1024){
    int r=idx/n, c=idx-r*n;
    double v=0.0;
    if (r==c+1){ double m=(double)(c-l); v = -0.5*sqrt((double)l*(l+1)-m*(m+1)); }
    else if (c==r+1){ double m=(double)(r-l); v = 0.5*sqrt((double)l*(l+1)-m*(m+1)); }
    A[idx] = v*(M_PI*0.5/128.0);
    T[idx] = (r==c)?1.0:0.0;
  }
  __syncthreads();
  for (int j=14; j>=1; --j){
    for (int idx=threadIdx.x; idx<n2; idx+=1024){
      int r=idx/n, c=idx-r*n; double acc=0.0;
      if (r>0)   acc += A[r*n+(r-1)]*T[(r-1)*n+c];
      if (r<n-1) acc += A[r*n+(r+1)]*T[(r+1)*n+c];
      Tm[idx]=acc;
    }
    __syncthreads();
    for (int idx=threadIdx.x; idx<n2; idx+=1024){
      int r=idx/n, c=idx-r*n;
      T[idx] = ((r==c)?1.0:0.0) + Tm[idx]/(double)j;
    }
    __syncthreads();
  }
  for (int s=0; s<7; ++s){
    for (int idx=threadIdx.x; idx<n2; idx+=1024){
      int r=idx/n, c=idx-r*n; double acc=0.0;
      for (int q=0;q<n;q++) acc += T[r*n+q]*T[q*n+c];
      Tm[idx]=acc;
    }
    __syncthreads();
    for (int idx=threadIdx.x; idx<n2; idx+=1024) T[idx]=Tm[idx];
    __syncthreads();
  }
  for (int idx=threadIdx.x; idx<n2; idx+=1024){ Dd[l*961+idx]=T[idx]; Df[l*961+idx]=(float)T[idx]; }
}

// ---------------- beta-grid Wigner tables from Delta ----------------
__global__ void k_tables(const double* Dd, const float* qw30, const float* qw16, const float* qw10,
                         float* wd_s2, float* dif16, float* wd16, float* dif10t,
                         const unsigned long long* __restrict__ tflag){
  if (tflag[0]==TBL_MAGIC) return;
  int bid=blockIdx.x;
  __shared__ double cc[32], ss[32];
  int l,k,mode; double beta;
  if (bid<960){ mode=0; l=bid/60; k=bid%60; beta=M_PI*(2*k+1)/120.0; }
  else if (bid<1472){ mode=1; int q=bid-960; l=q/32; k=q%32; beta=M_PI*(2*k+1)/64.0; }
  else { mode=2; int q=bid-1472; l=q/20; k=q%20; beta=M_PI*(2*k+1)/40.0; }
  int n=2*l+1;
  for (int kk=threadIdx.x; kk<=l; kk+=256){ cc[kk]=cos(kk*beta); ss[kk]=sin(kk*beta); }
  __syncthreads();
  const double* D = Dd + l*961;
  if (mode==0){
    for (int mm=threadIdx.x; mm<n; mm+=256){
      int m=mm-l; int p=((m)%4+4)%4; double s=0.0;
      for (int kk=-l; kk<=l; ++kk){
        int ak = kk<0?-kk:kk;
        double c=cc[ak], sn=(kk<0)?-ss[ak]:ss[ak];
        double f=(p==0)?c:(p==1)?sn:(p==2)?-c:-sn;
        s += D[(kk+l)*n+mm]*D[(kk+l)*n+l]*f;
      }
      wd_s2[(l*60+k)*31+mm] = (float)(s*(double)qw30[k]*(2.0*M_PI/60.0));
    }
  } else if (mode==1){
    for (int idx=threadIdx.x; idx<n*n; idx+=256){
      int mm=idx/n, nn=idx-mm*n; int m=mm-l, nb=nn-l;
      int p=((m-nb)%4+4)%4; double s=0.0;
      for (int kk=-l; kk<=l; ++kk){
        int ak = kk<0?-kk:kk;
        double c=cc[ak], sn=(kk<0)?-ss[ak]:ss[ak];
        double f=(p==0)?c:(p==1)?sn:(p==2)?-c:-sn;
        s += D[(kk+l)*n+mm]*D[(kk+l)*n+nn]*f;
      }
      dif16[(size_t)(l*32+k)*961+idx] = (float)((2*l+1)*s);
      if (l<10) wd16[(size_t)(l*32+k)*361+idx] = (float)(s*(double)qw16[k]*(2.0*M_PI/32.0)*(2.0*M_PI/32.0));
    }
  } else {
    for (int idx=threadIdx.x; idx<n*n; idx+=256){
      int mm=idx/n, nn=idx-mm*n; int m=mm-l, nb=nn-l;
      int p=((m-nb)%4+4)%4; double s=0.0;
      for (int kk=-l; kk<=l; ++kk){
        int ak = kk<0?-kk:kk;
        double c=cc[ak], sn=(kk<0)?-ss[ak]:ss[ak];
        double f=(p==0)?c:(p==1)?sn:(p==2)?-c:-sn;
        s += D[(kk+l)*n+mm]*D[(kk+l)*n+nn]*f;
      }
      if (mm>=l){
        int ms=mm-l, n9=nn-l+9;
        dif10t[((size_t)k*10+l)*190 + ms*19 + n9] = (float)((2*l+1)*s);
      }
    }
  }
}

// ---------------- prep: setflag + zero img/part ----------------
__global__ void k_prep(unsigned long long* tflag, float* img, double2* part){
  int gid = blockIdx.x*256 + threadIdx.x;
  if (gid==0) tflag[0]=TBL_MAGIC;
  for (int i=gid; i<28800; i+=8192) img[i]=0.f;
  for (int i=gid; i<800;   i+=8192) part[i]=make_double2(0.0,0.0);
}

// ---------------- project point cloud to S2 grid (max-scatter) ----------------
__global__ void k_project(const float* x, float* img){
  int tid = blockIdx.x*256+threadIdx.x;
  if (tid>=8192) return;
  int b=tid>>10, n=tid&1023;
  float px=x[(b*3+0)*1024+n], py=x[(b*3+1)*1024+n], pz=x[(b*3+2)*1024+n];
  float r = sqrtf(px*px+py*py+pz*pz);
  float rc = fmaxf(r, 1e-8f);
  float ct = fminf(1.f, fmaxf(-1.f, pz/rc));
  float beta = acosf(ct);
  float alpha = atan2f(py, px);
  const float TWO_PI = 6.283185307179586f;
  alpha = fmodf(alpha, TWO_PI); if (alpha<0.f) alpha += TWO_PI;
  int bi = (int)(beta/3.14159265358979323846f*60.f); bi = min(59, max(0, bi));
  int ai = (int)(alpha/TWO_PI*60.f);                 ai = min(59, max(0, ai));
  atomicMax((int*)&img[(b*60+bi)*60+ai], __float_as_int(r));
}

// ---------------- k_front: fused {s2a+s2b | yc | wh2} via block-range dispatch ----------------
__global__ __launch_bounds__(256) void k_front(const float* __restrict__ img, const float2* __restrict__ ph60,
                                               const float* __restrict__ wd_s2, float2* __restrict__ X,
                                               const float* __restrict__ w_s2, const float* __restrict__ Df,
                                               float2* __restrict__ YC,
                                               const float* __restrict__ w_so3, const float2* __restrict__ ph32g,
                                               float2* __restrict__ WH2){
  int bid=blockIdx.x; int t=threadIdx.x;
  if (bid<8){
    int b=bid;
    __shared__ float im[3600];
    __shared__ float2 G[960];
    __shared__ float2 ph[60];
    if (t<60) ph[t]=ph60[t];
    for (int i=t;i<3600;i+=256) im[i]=img[b*3600+i];
    __syncthreads();
    for (int i=t;i<960;i+=256){
      int k=i>>4, m=i&15;
      float sr=0.f, si=0.f;
      const float* imk=&im[k*60];
      for (int a=0;a<60;a++){ float v=imk[a]; float2 p=ph[(m*a)%60]; sr+=v*p.x; si-=v*p.y; }
      G[(k<<4)+m]=make_float2(sr,si);
    }
    __syncthreads();
    int off=t;
    int l=0; while((l+1)*(l+1)<=off) l++;
    int mm=off-l*l; int m=mm-l; int am = m<0?-m:m;
    float xr=0.f, xi=0.f;
    for (int k=0;k<60;k++){
      float w=wd_s2[(l*60+k)*31+mm];
      float2 g=G[(k<<4)+am];
      float gi = (m<0)? -g.y : g.y;
      xr += w*g.x; xi += w*gi;
    }
    X[b*256+off]=make_float2(xr,xi);
  } else if (bid<108){
    int f=bid-8;
    __shared__ float wv[60];
    __shared__ float2 W[16];
    for (int p=t;p<60;p+=256) wv[p]=w_s2[f*60+p];
    __syncthreads();
    if (t<16){
      float sr=0.f, si=0.f;
      for (int p=0;p<60;p++){ float2 p2=ph60[(t*p)%60]; sr+=wv[p]*p2.x; si-=wv[p]*p2.y; }
      W[t]=make_float2(sr/60.f, si/60.f);
    }
    __syncthreads();
    {
      int off=t;
      int l=0; while((l+1)*(l+1)<=off) l++;
      int mm=off-l*l; int m=mm-l; int am=m<0?-m:m;
      float dh=Df[l*961 + mm*(2*l+1) + l];
      float2 wm=W[am];
      float wi = (m>=0)? -wm.y : wm.y;
      YC[f*256+off]=make_float2(dh*wm.x, dh*wi);
    }
  } else {
    int tid=(bid-108)*256+t;
    if (tid<10000){
      int i=tid/100, o=tid-i*100;
      float wv2[32];
      for (int p=0;p<32;p++) wv2[p]=w_so3[(i*100+o)*32+p];
      for (int m=0;m<10;m++){
        float sr=0.f, si=0.f;
        for (int p=0;p<32;p++){ float2 p2=ph32g[(m*p)&31]; sr+=wv2[p]*p2.x; si-=wv2[p]*p2.y; }
        WH2[((size_t)m*100+i)*100+o]=make_float2(sr/32.f, si/32.f);
      }
    }
  }
}

// ---------------- u compact (ns>=0): writes PADDED layout [b,k][c*33+a] ----------------
__global__ void k_u(const float2* X, const float* dif16, const float2* ph32g, float2* u){
  int bid=blockIdx.x;
  int l, k, ns0, ns1;
  if (bid < 256){ l = bid>>5; k = bid&31; ns0=0; ns1=l+1; }
  else {
    int q=bid-256; l = 8 + (q>>6); int half=(q>>5)&1; k=q&31;
    int mid=(l+2)>>1;
    ns0 = half? mid : 0; ns1 = half? (l+1) : mid;
  }
  int n=2*l+1;
  __shared__ float d[961];
  __shared__ float2 Xs[8][31];
  __shared__ float2 ph[32];
  int t=threadIdx.x;
  if (t<32) ph[t]=ph32g[t];
  for (int i=t;i<n*n;i+=256) d[i]=dif16[(size_t)(l*32+k)*961+i];
  if (t<8*n){ int b=t/n, mm=t-b*n; Xs[b][mm]=X[b*256+l*l+mm]; }
  __syncthreads();
  int b=t>>5, a=t&31;
  float2* up = u + (size_t)(b*32+k)*4488 + a;
  for (int ns=ns0; ns<ns1; ++ns){
    float ar=0.f, ai=0.f;
    int nn = ns + l;
    for (int mm=0; mm<n; ++mm){
      float2 x=Xs[b][mm];
      float2 p=ph[((mm-l)*a)&31];
      float pr=x.x*p.x-x.y*p.y, pi=x.x*p.y+x.y*p.x;
      float dv=d[mm*n+nn];
      ar += dv*pr; ai += dv*pi;
    }
    up[(size_t)(c_T[l]+ns)*33]=make_float2(ar,ai);
  }
}

// ---------------- big inverse transform v9 (R17-proven): LDS-staged u2, g<->16-g folded stage C
#define KH_F 8
__global__ __launch_bounds__(512,4) void k_h(const float2* __restrict__ u, const float2* __restrict__ YC,
                                             float* __restrict__ h, double2* __restrict__ part){
  int bid=blockIdx.x;
  int fg = bid % 13; int rem = bid/13; int kp = rem & 15; int b = rem >> 4;
  int k0 = kp*2;
  int f0 = fg*KH_F; int F_act = (f0+KH_F<=100)? KH_F : (100-f0);

  __shared__ alignas(16) float2 u2[2][4488];
  __shared__ float2 ysc[KH_F*136];
  int t=threadIdx.x;

  {
    const float4* gs = (const float4*)(u + (size_t)(b*32+k0)*4488);
    float4* ls = (float4*)&u2[0][0];
    for (int j=t; j<4488; j+=512) ls[j]=gs[j];
  }
  for (int i=t; i<KH_F*136; i+=512){
    int fi=i/136, c=i-fi*136;
    float2 y=make_float2(0.f,0.f);
    if (fi<F_act){
      int l=l_from_T(c); int ns=c-c_T[l];
      y=YC[(size_t)(f0+fi)*256 + l*l+l+ns];
    }
    ysc[i]=y;
  }
  __syncthreads();

  int kk = t>>8, tt = t&255;
  float* vbase = (float*)&u2[kk][0];

  {
    int ns = tt>>4; int sub = tt&15; int ft = sub>>3; int at = sub&7;
    int a0 = at*4;
    const float2* uk = u2[kk];
    float ar[16], ai[16];
    #pragma unroll
    for (int q=0;q<16;q++){ ar[q]=0.f; ai[q]=0.f; }
    for (int l=ns; l<16; ++l){
      int c = c_T[l]+ns;
      float2 y0=ysc[(ft*4+0)*136+c];
      float2 y1=ysc[(ft*4+1)*136+c];
      float2 y2=ysc[(ft*4+2)*136+c];
      float2 y3=ysc[(ft*4+3)*136+c];
      float2 U0=uk[c*33+a0+0];
      float2 U1=uk[c*33+a0+1];
      float2 U2=uk[c*33+a0+2];
      float2 U3=uk[c*33+a0+3];
      #define CM(j,Y,i_,Ui) \
        ar[(j)*4+(i_)] += (Y).x*(Ui).x - (Y).y*(Ui).y; \
        ai[(j)*4+(i_)] += (Y).x*(Ui).y + (Y).y*(Ui).x;
      CM(0,y0,0,U0) CM(0,y0,1,U1) CM(0,y0,2,U2) CM(0,y0,3,U3)
      CM(1,y1,0,U0) CM(1,y1,1,U1) CM(1,y1,2,U2) CM(1,y1,3,U3)
      CM(2,y2,0,U0) CM(2,y2,1,U1) CM(2,y2,2,U2) CM(2,y2,3,U3)
      CM(3,y3,0,U0) CM(3,y3,1,U1) CM(3,y3,2,U2) CM(3,y3,3,U3)
      #undef CM
    }
    __syncthreads();
    float* vr = vbase;
    float* vi = vbase + 4352;
    #pragma unroll
    for (int j=0;j<4;j++){
      #pragma unroll
      for (int i=0;i<4;i++){
        int fi=ft*4+j, a=a0+i;
        vr[(fi*32+a)*17+ns]=ar[j*4+i];
        vi[(fi*32+a)*17+ns]=ai[j*4+i];
      }
    }
  }
  __syncthreads();

  {
    const float* vr = vbase;
    const float* vi = vbase + 4352;
    int fi=tt>>5, a=tt&31;
    float xr[16], xi[16];
    #pragma unroll
    for (int ns=0;ns<16;ns++){ xr[ns]=vr[(fi*32+a)*17+ns]; xi[ns]=vi[(fi*32+a)*17+ns]; }
    float vr0 = xr[0];
    bool wr = (fi<F_act);
    float* hp = h + ((size_t)(b*100+f0+fi)*32 + (k0+kk))*1024 + a;
    float sf=0.f, qf=0.f;
    #define EMIT(gidx, hv) { float hv_=(hv); if(wr) hp[(gidx)*32]=hv_; sf+=hv_; qf+=hv_*hv_; }
    {
      float se=0.f, so=0.f;
      #pragma unroll
      for (int ns=0; ns<16; ++ns){ if (ns&1) so+=xr[ns]; else se+=xr[ns]; }
      EMIT(0,  2.f*(se+so)-vr0);
      EMIT(16, 2.f*(se-so)-vr0);
    }
    {
      float se=0.f, so=0.f;
      #pragma unroll
      for (int ns=0; ns<16; ++ns){
        const int idx=(ns*8)&31;
        float term = xr[ns]*CS32[idx] - xi[ns]*SN32[idx];
        if (ns&1) so+=term; else se+=term;
      }
      EMIT(8,  2.f*(se+so)-vr0);
      EMIT(24, 2.f*(se-so)-vr0);
    }
    #pragma unroll
    for (int g=1; g<8; ++g){
      float SAe=0.f, SBe=0.f, SAo=0.f, SBo=0.f;
      #pragma unroll
      for (int ns=0; ns<16; ++ns){
        const int idx=(ns*g)&31;
        float A = xr[ns]*CS32[idx];
        float B = xi[ns]*SN32[idx];
        if (ns&1){ SAo+=A; SBo+=B; } else { SAe+=A; SBe+=B; }
      }
      float se1=SAe-SBe, so1=SAo-SBo;
      float se2=SAe+SBe, so2=-(SAo+SBo);
      EMIT(g,      2.f*(se1+so1)-vr0);
      EMIT(g+16,   2.f*(se1-so1)-vr0);
      EMIT(16-g,   2.f*(se2+so2)-vr0);
      EMIT(32-g,   2.f*(se2-so2)-vr0);
    }
    #undef EMIT
    for (int d=16; d>0; d>>=1){ sf += __shfl_down(sf, d, 32); qf += __shfl_down(qf, d, 32); }
    if (a==0 && fi<F_act){
      atomicAdd(&part[b*100+f0+fi].x, (double)sf);
      atomicAdd(&part[b*100+f0+fi].y, (double)qf);
    }
  }
}

// ---------------- BN scale/shift from partials; self-zeroes part ----------------
__global__ void k_bn2(const double2* __restrict__ partial, int per, const float* g, const float* bb,
                      float* scale, float* shift, double2* partial_w){
  int f=blockIdx.x*64+threadIdx.x;
  if (f>=100) return;
  double s=0.0, q=0.0;
  for (int b=0;b<8;b++){ double2 v=partial[b*100+f]; s+=v.x; q+=v.y; }
  for (int b=0;b<8;b++){ partial_w[b*100+f]=make_double2(0.0,0.0); }
  double cnt=8.0*(double)per;
  double mu=s/cnt, var=q/cnt-mu*mu;
  double sc=(double)g[f]/sqrt(var+1e-5);
  scale[f]=(float)sc; shift[f]=(float)((double)bb[f]-mu*sc);
}

// ---------------- k_g v3b: block = (bc, k-quad), 256 thr = 4 waves ----------------
template<int M0>
__device__ __forceinline__ void alpha_dft(const float* __restrict__ yk, float2* __restrict__ tdst, int g){
  float ax0=0.f,ay0=0.f, ax1=0.f,ay1=0.f, ax2=0.f,ay2=0.f, ax3=0.f,ay3=0.f, ax4=0.f,ay4=0.f;
  #pragma unroll
  for (int a=0;a<16;a++){
    float ya=yk[a], yb=yk[a+16];
    float yp=ya+yb, ym=ya-yb;
    #define AM(mi, AX, AY) { \
      const int m_ = M0+mi; \
      const int idx_ = (m_*a)&31; \
      float v_ = (m_&1)? ym : yp; \
      AX += v_*CS32[idx_]; \
      AY -= v_*SN32[idx_]; }
    AM(0,ax0,ay0) AM(1,ax1,ay1) AM(2,ax2,ay2) AM(3,ax3,ay3) AM(4,ax4,ay4)
    #undef AM
  }
  tdst[(M0+0)*33+g]=make_float2(ax0,ay0);
  tdst[(M0+1)*33+g]=make_float2(ax1,ay1);
  tdst[(M0+2)*33+g]=make_float2(ax2,ay2);
  tdst[(M0+3)*33+g]=make_float2(ax3,ay3);
  tdst[(M0+4)*33+g]=make_float2(ax4,ay4);
}

__global__ __launch_bounds__(256) void k_g(const float* __restrict__ h, const float* __restrict__ scale,
                                           const float* __restrict__ shift, const float2* __restrict__ ph32g,
                                           float2* __restrict__ G){
  int bid=blockIdx.x; int kq=bid&7; int bc=bid>>3; int c=bc%100;
  int k0 = kq*4;
  __shared__ float y[4][32*33];
  __shared__ float2 tsc[4][10*33];
  int t=threadIdx.x;
  float sc=scale[c], sh=shift[c];
  {
    const float4* h4 = (const float4*)(h + (size_t)bc*32768 + (size_t)k0*1024);
    for (int i=t;i<1024;i+=256){
      float4 v=h4[i];
      int base=i<<2;
      int kk=base>>10, idx=base&1023, g=idx>>5, a=idx&31;
      float* yw=&y[kk][g*33+a];
      yw[0]=fmaxf(v.x*sc+sh, 0.f);
      yw[1]=fmaxf(v.y*sc+sh, 0.f);
      yw[2]=fmaxf(v.z*sc+sh, 0.f);
      yw[3]=fmaxf(v.w*sc+sh, 0.f);
    }
  }
  __syncthreads();
  int wid=t>>6, lane=t&63;
  {
    int mh=wid&1, kh=wid>>1;
    int kk=kh*2+(lane>>5), g=lane&31;
    const float* yk=&y[kk][g*33];
    if (mh==0) alpha_dft<0>(yk, tsc[kk], g);
    else       alpha_dft<5>(yk, tsc[kk], g);
  }
  __syncthreads();
  if (lane<50){
    int kk=wid;
    int mrow=lane/5, p=lane%5;
    int sa=2*p+1, sb=(p==4)? 0 : 2*p+2;
    const float2* tk=&tsc[kk][mrow*33];
    float2 stA=ph32g[sa];
    float2 stB=ph32g[sb];
    float Aa=0.f,Ba=0.f,Ca=0.f,Da=0.f, Ab=0.f,Bb=0.f,Cb=0.f,Db=0.f;
    #pragma unroll
    for (int half=0; half<2; ++half){
      int ea=(sa*half)&3, eb=(sb*half)&3;
      float2 qa=make_float2(ea==0?1.f:(ea==2?-1.f:0.f), ea==1?1.f:(ea==3?-1.f:0.f));
      float2 qb=make_float2(eb==0?1.f:(eb==2?-1.f:0.f), eb==1?1.f:(eb==3?-1.f:0.f));
      #pragma unroll
      for (int g8=0; g8<8; ++g8){
        int g=half*8+g8;
        float2 ta=tk[g], tb=tk[g+16];
        float tpx=ta.x+tb.x, tpy=ta.y+tb.y;
        float tmx=ta.x-tb.x, tmy=ta.y-tb.y;
        Aa += tmx*qa.x; Ba += tmy*qa.y; Ca += tmy*qa.x; Da += tmx*qa.y;
        Ab += tpx*qb.x; Bb += tpy*qb.y; Cb += tpy*qb.x; Db += tpx*qb.y;
        float nax=qa.x*stA.x - qa.y*stA.y, nay=qa.x*stA.y + qa.y*stA.x; qa=make_float2(nax,nay);
        float nbx=qb.x*stB.x - qb.y*stB.y, nby=qb.x*stB.y + qb.y*stB.x; qb=make_float2(nbx,nby);
      }
    }
    float2* Gp = G + (size_t)(bc*32 + k0+kk)*190 + mrow*19;
    Gp[9+sa]=make_float2(Aa+Ba, Ca-Da);
    Gp[9-sa]=make_float2(Aa-Ba, Ca+Da);
    Gp[9+sb]=make_float2(Ab+Bb, Cb-Db);
    Gp[9-sb]=make_float2(Ab-Bb, Cb+Db);
  }
}

// ---------------- k_xa: FUSED k_x2 + k_A through LDS (X2 global round-trip eliminated).
// Block per bc: stage G[bc] (48.6KB), compute X2 row into LDS (identical math/order to k_x2),
// barrier, compute A outputs (identical 2-way-unrolled dot to k_A). LDS 54.4KB -> 2 blocks/CU.
__global__ __launch_bounds__(256) void k_xa(const float2* __restrict__ G, const float* __restrict__ wd16,
                                            const float* __restrict__ Df, float2* __restrict__ A){
  int bc=blockIdx.x;
  __shared__ float2 Gs[6080];
  __shared__ float2 X2s[715];
  int t=threadIdx.x;
  for (int idx=t; idx<6080; idx+=256) Gs[idx]=G[(size_t)bc*6080+idx];
  __syncthreads();
  for (int i=t; i<715; i+=256){
    int l=l_from_offH(i); int rem=i-c_offH[l]; int n=2*l+1;
    int m=rem/n, kk2=rem-m*n; int ng=kk2-l;
    int j = m*19+(ng+9);
    const float* wp = wd16 + (size_t)l*32*361 + (m+l)*n + kk2;
    float ar=0.f, ai=0.f;
    #pragma unroll 8
    for (int k=0;k<32;k++){
      float2 gv=Gs[k*190+j];
      float  wv=wp[(size_t)k*361];
      ar += wv*gv.x; ai += wv*gv.y;
    }
    X2s[i]=make_float2(ar, ai);
  }
  __syncthreads();
  for (int off=t; off<715; off+=256){
    int l = l_from_offH(off); int rem = off - c_offH[l]; int n = 2*l+1;
    int m = rem/n, nn = rem - m*n;
    const float2* Xp = &X2s[c_offH[l] + m*n];
    const float* Dp = Df + l*961 + nn*n;
    float ar=0.f, ai=0.f;
    float br=0.f, bis=0.f;
    int kk=0;
    for (; kk+1<n; kk+=2){
      float2 x0 = Xp[kk];   float d0 = Dp[kk];
      float2 x1 = Xp[kk+1]; float d1 = Dp[kk+1];
      ar += x0.x*d0; ai += x0.y*d0;
      br += x1.x*d1; bis += x1.y*d1;
    }
    if (kk<n){ float2 x = Xp[kk]; float dv = Dp[kk]; ar += x.x*dv; ai += x.y*dv; }
    A[(size_t)bc*715+off] = make_float2(ar+br, ai+bis);
  }
}

// ---------------- Z2 (half rows): Z2h = sum_i A * conj(What2) ----------------
__global__ void k_z2(const float2* A, const float2* WH2, float2* Z2){
  int bid=blockIdx.x; int b=bid&7; int r=bid>>3;
  int l=l_from_sq(r); int nn=r-l*l; int n=2*l+1; int ns=nn-l;
  int nrow=l+1;
  __shared__ float2 As[100*10];
  int t=threadIdx.x;
  for (int idx=t; idx<100*nrow; idx+=256){
    int i=idx/nrow, m=idx-i*nrow;
    As[idx]=A[(size_t)(b*100+i)*715 + c_offH[l] + m*n + nn];
  }
  __syncthreads();
  int mabs = ns<0?-ns:ns;
  const float2* Wp = WH2 + (size_t)mabs*10000;
  float sgn = (ns>=0)? -1.f : 1.f;
  for (int idx=t; idx<100*nrow; idx+=256){
    int o=idx/nrow, m=idx-o*nrow;
    float zr=0.f, zi=0.f;
    #pragma unroll 4
    for (int i=0;i<100;i++){
      float2 a=As[i*nrow+m];
      float2 w=Wp[i*100+o]; float wr=w.x, wi=sgn*w.y;
      zr += a.x*wr - a.y*wi;
      zi += a.x*wi + a.y*wr;
    }
    Z2[(size_t)(b*100+o)*715 + c_offH[l] + m*n + nn]=make_float2(zr,zi);
  }
}

// ---------------- fused SO3 IFFT at b=10 v6: k-PAIRED blocks (256 thr) ----------------
__global__ __launch_bounds__(256) void k_ifft10(const float2* __restrict__ Z2, const float* __restrict__ dif10t,
                                                const float2* __restrict__ ph20g, float* __restrict__ h2,
                                                double2* __restrict__ part){
  int bid=blockIdx.x; int bf=bid/10, kp=bid-10*bf;
  int k0=kp*2;
  __shared__ float2 Zs[715];
  __shared__ float2 M[2][190];
  __shared__ float2 T[2][200];
  __shared__ float2 ph[20];
  __shared__ float rs[256], rq[256];
  int t=threadIdx.x;
  if (t<20) ph[t]=ph20g[t];
  const float2* Zp = Z2 + (size_t)bf*715;
  for (int i=t;i<715;i+=256) Zs[i]=Zp[i];
  __syncthreads();
  {
    int kk = t>>7, tt = t&127;
    int k = k0+kk;
    for (int i=tt;i<190;i+=128){
      int ms=i/19, n9=i-ms*19; int nsg=n9-9;
      int a2=nsg<0?-nsg:nsg; int l0 = ms>a2?ms:a2;
      float mr=0.f, mi=0.f;
      const float* dp = dif10t + (size_t)k*1900 + i;
      for (int l=l0;l<10;l++){
        float dv=dp[l*190];
        float2 z=Zs[c_offH[l] + ms*(2*l+1) + nsg + l];
        mr += dv*z.x; mi += dv*z.y;
      }
      M[kk][i]=make_float2(mr,mi);
    }
  }
  __syncthreads();
  if (t<200){
    int kk=t/100, j=t-100*kk;
    int g=j/5, ms0=(j%5)*2;
    const float2* Mp0=&M[kk][ms0*19];
    const float2* Mp1=Mp0+19;
    float2 stp=ph[g];
    float2 p=ph[(11*g)%20];
    float tr0=0.f,ti0=0.f,tr1=0.f,ti1=0.f;
    #pragma unroll
    for (int n9=0;n9<19;n9++){
      float2 m0=Mp0[n9], m1=Mp1[n9];
      tr0 += m0.x*p.x - m0.y*p.y;
      ti0 += m0.x*p.y + m0.y*p.x;
      tr1 += m1.x*p.x - m1.y*p.y;
      ti1 += m1.x*p.y + m1.y*p.x;
      float nx=p.x*stp.x - p.y*stp.y, ny=p.x*stp.y + p.y*stp.x;
      p=make_float2(nx,ny);
    }
    T[kk][ms0*20+g]=make_float2(tr0,ti0);
    T[kk][(ms0+1)*20+g]=make_float2(tr1,ti1);
  }
  __syncthreads();
  float sf=0.f, qf=0.f;
  if (t<200){
    int kk=t/100, j=t-100*kk;
    int a=j/5, g0=(j%5)*4;
    const float2* Tk=&T[kk][0];
    float acc0=Tk[g0].x, acc1=Tk[g0+1].x, acc2=Tk[g0+2].x, acc3=Tk[g0+3].x;
    float2 stp=ph[a];
    float2 p=stp;
    #pragma unroll
    for (int ms=1; ms<10; ++ms){
      const float2* Tp=&Tk[ms*20+g0];
      float2 t0=Tp[0], t1=Tp[1], t2=Tp[2], t3=Tp[3];
      acc0 += 2.f*(t0.x*p.x - t0.y*p.y);
      acc1 += 2.f*(t1.x*p.x - t1.y*p.y);
      acc2 += 2.f*(t2.x*p.x - t2.y*p.y);
      acc3 += 2.f*(t3.x*p.x - t3.y*p.y);
      float nx=p.x*stp.x - p.y*stp.y, ny=p.x*stp.y + p.y*stp.x;
      p=make_float2(nx,ny);
    }
    float* hp = h2 + (size_t)bf*8000 + (k0+kk)*400 + a*20 + g0;
    *(float4*)hp = make_float4(acc0,acc1,acc2,acc3);
    sf = acc0+acc1+acc2+acc3;
    qf = acc0*acc0+acc1*acc1+acc2*acc2+acc3*acc3;
  }
  rs[t]=sf; rq[t]=qf; __syncthreads();
  for (int w=128;w>0;w>>=1){ if(t<w){rs[t]+=rs[t+w]; rq[t]+=rq[t+w];} __syncthreads(); }
  if (t==0){
    atomicAdd(&part[bf].x, (double)rs[0]);
    atomicAdd(&part[bf].y, (double)rq[0]);
  }
}

// ---------------- BN2+ReLU + SO3 integrate -> feat ----------------
__global__ void k_integrate(const float* h2, const float* scale, const float* shift, const float* qw10, float* feat){
  int bf=blockIdx.x; int f=bf%100; int t=threadIdx.x;
  float sc=scale[f], sh=shift[f];
  const float4* p4=(const float4*)(h2+(size_t)bf*8000);
  float s=0.f;
  for (int i4=t;i4<2000;i4+=256){
    float4 v=p4[i4];
    float qw=qw10[i4/100];
    float r0=fmaxf(v.x*sc+sh,0.f);
    float r1=fmaxf(v.y*sc+sh,0.f);
    float r2=fmaxf(v.z*sc+sh,0.f);
    float r3=fmaxf(v.w*sc+sh,0.f);
    s += (r0+r1+r2+r3)*qw;
  }
  __shared__ float r[256];
  r[t]=s; __syncthreads();
  for (int w=128;w>0;w>>=1){ if(t<w) r[t]+=r[t+w]; __syncthreads(); }
  if (t==0){
    float c=(float)((2.0*M_PI/20.0)*(2.0*M_PI/20.0));
    feat[bf]=r[0]*c;
  }
}

// ---------------- final linear ----------------
__global__ void k_logits(const float* feat, const float* lw, const float* lb, float* out){
  int t=blockIdx.x*64+threadIdx.x;
  if (t>=320) return;
  int b=t/40, c=t-40*b;
  float s=lb[c];
  for (int f=0;f<100;f++) s += feat[b*100+f]*lw[f*40+c];
  out[t]=s;
}

extern "C" void kernel_launch(void* const* d_in, const int* in_sizes, int n_in,
                              void* d_out, int out_size, void* d_ws, size_t ws_size,
                              hipStream_t stream){
  (void)in_sizes; (void)n_in; (void)out_size; (void)ws_size;
  const float* x    = (const float*)d_in[0];
  const float* w_s2 = (const float*)d_in[1];
  const float* bn1g = (const float*)d_in[3];
  const float* bn1b = (const float*)d_in[4];
  const float* w_so3= (const float*)d_in[5];
  const float* bn2g = (const float*)d_in[7];
  const float* bn2b = (const float*)d_in[8];
  const float* linw = (const float*)d_in[9];
  const float* linb = (const float*)d_in[10];
  float* out = (float*)d_out;

  char* base=(char*)d_ws; size_t off=0;
  auto alloc=[&](size_t bytes)->void*{ void* p=base+off; off=(off+bytes+255)&~(size_t)255; return p; };
  double* Dd   = (double*)alloc((size_t)16*961*8);
  float*  Df   = (float*) alloc((size_t)16*961*4);
  float*  qw30 = (float*) alloc(256);
  float*  qw16 = (float*) alloc(256);
  float*  qw10 = (float*) alloc(256);
  float2* ph60 = (float2*)alloc(512);
  float2* ph32 = (float2*)alloc(256);
  float2* ph20 = (float2*)alloc(256);
  float*  wd_s2= (float*) alloc((size_t)16*60*31*4);
  float*  dif16= (float*) alloc((size_t)16*32*961*4);
  float*  wd16 = (float*) alloc((size_t)10*32*361*4);
  float*  dif10t=(float*) alloc((size_t)20*10*190*4);
  float*  img  = (float*) alloc((size_t)8*3600*4);
  float2* X    = (float2*)alloc((size_t)8*256*8);
  float2* YC   = (float2*)alloc((size_t)100*256*8);
  float2* u    = (float2*)alloc((size_t)8*32*4488*8);
  float*  h    = (float*) alloc((size_t)8*100*32768*4);
  float*  sc1  = (float*) alloc(512);
  float*  sh1  = (float*) alloc(512);
  float2* Gbuf = (float2*)alloc((size_t)800*32*190*8);
  float2* WH2  = (float2*)alloc((size_t)10*100*100*8);
  float2* A    = (float2*)alloc((size_t)800*715*8);
  float2* Z2   = (float2*)alloc((size_t)800*715*8);
  float*  h2   = (float*) alloc((size_t)8*100*8000*4);
  float*  sc2  = (float*) alloc(512);
  float*  sh2  = (float*) alloc(512);
  float*  feat = (float*) alloc(4096);
  double2* part= (double2*)alloc((size_t)800*16);
  unsigned long long* tflag = (unsigned long long*)alloc(256);

  k_dq<<<17, 1024, 0, stream>>>(Dd, Df, qw30, qw16, qw10, ph32, ph20, ph60, tflag);
  k_tables<<<1672, 256, 0, stream>>>(Dd, qw30, qw16, qw10, wd_s2, dif16, wd16, dif10t, tflag);
  k_prep<<<32, 256, 0, stream>>>(tflag, img, part);
  k_project<<<32, 256, 0, stream>>>(x, img);
  k_front<<<148, 256, 0, stream>>>(img, ph60, wd_s2, X, w_s2, Df, YC, w_so3, ph32, WH2);
  k_u<<<768, 256, 0, stream>>>(X, dif16, ph32, u);
  k_h<<<8*16*13, 512, 0, stream>>>(u, YC, h, part);
  k_bn2<<<2, 64, 0, stream>>>(part, 32768, bn1g, bn1b, sc1, sh1, part);
  k_g<<<800*8, 256, 0, stream>>>(h, sc1, sh1, ph32, Gbuf);
  k_xa<<<800, 256, 0, stream>>>(Gbuf, wd16, Df, A);
  k_z2<<<800, 256, 0, stream>>>(A, WH2, Z2);
  k_ifft10<<<8000, 256, 0, stream>>>(Z2, dif10t, ph20, h2, part);
  k_bn2<<<2, 64, 0, stream>>>(part, 8000, bn2g, bn2b, sc2, sh2, part);
  k_integrate<<<800, 256, 0, stream>>>(h2, sc2, sh2, qw10, feat);
  k_logits<<<5, 64, 0, stream>>>(feat, linw, linb, out);
}

// Round 21
// 401.853 us; speedup vs baseline: 1.0152x; 1.0152x over previous
//
#include <hip/hip_runtime.h>
#include <math.h>

#ifndef M_PI
#define M_PI 3.14159265358979323846
#endif

#define TBL_MAGIC 0x5EED5EEDCAFEF00EULL

__device__ const int c_off2[11] = {0,1,10,35,84,165,286,455,680,969,1330};
__device__ const int c_offH[11] = {0,1,7,22,50,95,161,252,372,525,715};
__device__ const int c_T[17] = {0,1,3,6,10,15,21,28,36,45,55,66,78,91,105,120,136};

__device__ constexpr float CS32[32] = {
  1.0f, 0.98078528f, 0.92387953f, 0.83146961f, 0.70710678f, 0.55557023f, 0.38268343f, 0.19509032f,
  0.0f,-0.19509032f,-0.38268343f,-0.55557023f,-0.70710678f,-0.83146961f,-0.92387953f,-0.98078528f,
 -1.0f,-0.98078528f,-0.92387953f,-0.83146961f,-0.70710678f,-0.55557023f,-0.38268343f,-0.19509032f,
  0.0f, 0.19509032f, 0.38268343f, 0.55557023f, 0.70710678f, 0.83146961f, 0.92387953f, 0.98078528f};
__device__ constexpr float SN32[32] = {
  0.0f, 0.19509032f, 0.38268343f, 0.55557023f, 0.70710678f, 0.83146961f, 0.92387953f, 0.98078528f,
  1.0f, 0.98078528f, 0.92387953f, 0.83146961f, 0.70710678f, 0.55557023f, 0.38268343f, 0.19509032f,
  0.0f,-0.19509032f,-0.38268343f,-0.55557023f,-0.70710678f,-0.83146961f,-0.92387953f,-0.98078528f,
 -1.0f,-0.98078528f,-0.92387953f,-0.83146961f,-0.70710678f,-0.55557023f,-0.38268343f,-0.19509032f};

__device__ __forceinline__ int l_from_sq(int off){ int l=0; while((l+1)*(l+1)<=off) l++; return l; }
__device__ __forceinline__ int l_from_offH(int off){ int l=0; while(c_offH[l+1]<=off) l++; return l; }
__device__ __forceinline__ int l_from_T(int c){ int l=0; while(c_T[l+1]<=c) l++; return l; }

// ---------------- k_dq: fused Wigner Delta (blocks 0-15) + qw/phase tables (block 16) ----------------
__global__ void k_dq(double* Dd, float* Df, float* qw30, float* qw16, float* qw10,
                     float2* ph32, float2* ph20, float2* ph60,
                     const unsigned long long* __restrict__ tflag){
  if (tflag[0]==TBL_MAGIC) return;
  if (blockIdx.x==16){
    int t=threadIdx.x;
    if (t<60){
      double beta=M_PI*(2*t+1)/120.0, s=0.0;
      for (int j=0;j<30;j++) s += sin((double)(2*t+1)*(2*j+1)*M_PI/120.0)/(double)(2*j+1);
      qw30[t]=(float)((2.0/30.0)*sin(beta)*s);
      double a=2.0*M_PI*t/60.0; ph60[t]=make_float2((float)cos(a),(float)sin(a));
    }
    if (t<32){
      double beta=M_PI*(2*t+1)/64.0, s=0.0;
      for (int j=0;j<16;j++) s += sin((double)(2*t+1)*(2*j+1)*M_PI/64.0)/(double)(2*j+1);
      qw16[t]=(float)((2.0/16.0)*sin(beta)*s);
      double a=2.0*M_PI*t/32.0; ph32[t]=make_float2((float)cos(a),(float)sin(a));
    }
    if (t<20){
      double beta=M_PI*(2*t+1)/40.0, s=0.0;
      for (int j=0;j<10;j++) s += sin((double)(2*t+1)*(2*j+1)*M_PI/40.0)/(double)(2*j+1);
      qw10[t]=(float)((2.0/10.0)*sin(beta)*s);
      double a=2.0*M_PI*t/20.0; ph20[t]=make_float2((float)cos(a),(float)sin(a));
    }
    return;
  }
  int l = blockIdx.x; int n = 2*l+1; int n2=n*n;
  __shared__ double A[961], T[961], Tm[961];
  for (int idx=threadIdx.x; idx<n2; idx+=1024){
    int r=idx/n, c=idx-r*n;
    double v=0.0;
    if (r==c+1){ double m=(double)(c-l); v = -0.5*sqrt((double)l*(l+1)-m*(m+1)); }
    else if (c==r+1){ double m=(double)(r-l); v = 0.5*sqrt((double)l*(l+1)-m*(m+1)); }
    A[idx] = v*(M_PI*0.5/128.0);
    T[idx] = (r==c)?1.0:0.0;
  }
  __syncthreads();
  for (int j=14; j>=1; --j){
    for (int idx=threadIdx.x; idx<n2; idx+=1024){
      int r=idx/n, c=idx-r*n; double acc=0.0;
      if (r>0)   acc += A[r*n+(r-1)]*T[(r-1)*n+c];
      if (r<n-1) acc += A[r*n+(r+1)]*T[(r+1)*n+c];
      Tm[idx]=acc;
    }
    __syncthreads();
    for (int idx=threadIdx.x; idx<n2; idx+=1024){
      int r=idx/n, c=idx-r*n;
      T[idx] = ((r==c)?1.0:0.0) + Tm[idx]/(double)j;
    }
    __syncthreads();
  }
  for (int s=0; s<7; ++s){
    for (int idx=threadIdx.x; idx<n2; idx+=1024){
      int r=idx/n, c=idx-r*n; double acc=0.0;
      for (int q=0;q<n;q++) acc += T[r*n+q]*T[q*n+c];
      Tm[idx]=acc;
    }
    __syncthreads();
    for (int idx=threadIdx.x; idx<n2; idx+=1024) T[idx]=Tm[idx];
    __syncthreads();
  }
  for (int idx=threadIdx.x; idx<n2; idx+=1024){ Dd[l*961+idx]=T[idx]; Df[l*961+idx]=(float)T[idx]; }
}

// ---------------- beta-grid Wigner tables from Delta ----------------
__global__ void k_tables(const double* Dd, const float* qw30, const float* qw16, const float* qw10,
                         float* wd_s2, float* dif16, float* wd16, float* dif10t,
                         const unsigned long long* __restrict__ tflag){
  if (tflag[0]==TBL_MAGIC) return;
  int bid=blockIdx.x;
  __shared__ double cc[32], ss[32];
  int l,k,mode; double beta;
  if (bid<960){ mode=0; l=bid/60; k=bid%60; beta=M_PI*(2*k+1)/120.0; }
  else if (bid<1472){ mode=1; int q=bid-960; l=q/32; k=q%32; beta=M_PI*(2*k+1)/64.0; }
  else { mode=2; int q=bid-1472; l=q/20; k=q%20; beta=M_PI*(2*k+1)/40.0; }
  int n=2*l+1;
  for (int kk=threadIdx.x; kk<=l; kk+=256){ cc[kk]=cos(kk*beta); ss[kk]=sin(kk*beta); }
  __syncthreads();
  const double* D = Dd + l*961;
  if (mode==0){
    for (int mm=threadIdx.x; mm<n; mm+=256){
      int m=mm-l; int p=((m)%4+4)%4; double s=0.0;
      for (int kk=-l; kk<=l; ++kk){
        int ak = kk<0?-kk:kk;
        double c=cc[ak], sn=(kk<0)?-ss[ak]:ss[ak];
        double f=(p==0)?c:(p==1)?sn:(p==2)?-c:-sn;
        s += D[(kk+l)*n+mm]*D[(kk+l)*n+l]*f;
      }
      wd_s2[(l*60+k)*31+mm] = (float)(s*(double)qw30[k]*(2.0*M_PI/60.0));
    }
  } else if (mode==1){
    for (int idx=threadIdx.x; idx<n*n; idx+=256){
      int mm=idx/n, nn=idx-mm*n; int m=mm-l, nb=nn-l;
      int p=((m-nb)%4+4)%4; double s=0.0;
      for (int kk=-l; kk<=l; ++kk){
        int ak = kk<0?-kk:kk;
        double c=cc[ak], sn=(kk<0)?-ss[ak]:ss[ak];
        double f=(p==0)?c:(p==1)?sn:(p==2)?-c:-sn;
        s += D[(kk+l)*n+mm]*D[(kk+l)*n+nn]*f;
      }
      dif16[(size_t)(l*32+k)*961+idx] = (float)((2*l+1)*s);
      if (l<10) wd16[(size_t)(l*32+k)*361+idx] = (float)(s*(double)qw16[k]*(2.0*M_PI/32.0)*(2.0*M_PI/32.0));
    }
  } else {
    for (int idx=threadIdx.x; idx<n*n; idx+=256){
      int mm=idx/n, nn=idx-mm*n; int m=mm-l, nb=nn-l;
      int p=((m-nb)%4+4)%4; double s=0.0;
      for (int kk=-l; kk<=l; ++kk){
        int ak = kk<0?-kk:kk;
        double c=cc[ak], sn=(kk<0)?-ss[ak]:ss[ak];
        double f=(p==0)?c:(p==1)?sn:(p==2)?-c:-sn;
        s += D[(kk+l)*n+mm]*D[(kk+l)*n+nn]*f;
      }
      if (mm>=l){
        int ms=mm-l, n9=nn-l+9;
        dif10t[((size_t)k*10+l)*190 + ms*19 + n9] = (float)((2*l+1)*s);
      }
    }
  }
}

// ---------------- prep: setflag + zero img/part ----------------
__global__ void k_prep(unsigned long long* tflag, float* img, double2* part){
  int gid = blockIdx.x*256 + threadIdx.x;
  if (gid==0) tflag[0]=TBL_MAGIC;
  for (int i=gid; i<28800; i+=8192) img[i]=0.f;
  for (int i=gid; i<800;   i+=8192) part[i]=make_double2(0.0,0.0);
}

// ---------------- project point cloud to S2 grid (max-scatter) ----------------
__global__ void k_project(const float* x, float* img){
  int tid = blockIdx.x*256+threadIdx.x;
  if (tid>=8192) return;
  int b=tid>>10, n=tid&1023;
  float px=x[(b*3+0)*1024+n], py=x[(b*3+1)*1024+n], pz=x[(b*3+2)*1024+n];
  float r = sqrtf(px*px+py*py+pz*pz);
  float rc = fmaxf(r, 1e-8f);
  float ct = fminf(1.f, fmaxf(-1.f, pz/rc));
  float beta = acosf(ct);
  float alpha = atan2f(py, px);
  const float TWO_PI = 6.283185307179586f;
  alpha = fmodf(alpha, TWO_PI); if (alpha<0.f) alpha += TWO_PI;
  int bi = (int)(beta/3.14159265358979323846f*60.f); bi = min(59, max(0, bi));
  int ai = (int)(alpha/TWO_PI*60.f);                 ai = min(59, max(0, ai));
  atomicMax((int*)&img[(b*60+bi)*60+ai], __float_as_int(r));
}

// ---------------- k_front: fused {s2a+s2b | yc | wh2} via block-range dispatch ----------------
__global__ __launch_bounds__(256) void k_front(const float* __restrict__ img, const float2* __restrict__ ph60,
                                               const float* __restrict__ wd_s2, float2* __restrict__ X,
                                               const float* __restrict__ w_s2, const float* __restrict__ Df,
                                               float2* __restrict__ YC,
                                               const float* __restrict__ w_so3, const float2* __restrict__ ph32g,
                                               float2* __restrict__ WH2){
  int bid=blockIdx.x; int t=threadIdx.x;
  if (bid<8){
    int b=bid;
    __shared__ float im[3600];
    __shared__ float2 G[960];
    __shared__ float2 ph[60];
    if (t<60) ph[t]=ph60[t];
    for (int i=t;i<3600;i+=256) im[i]=img[b*3600+i];
    __syncthreads();
    for (int i=t;i<960;i+=256){
      int k=i>>4, m=i&15;
      float sr=0.f, si=0.f;
      const float* imk=&im[k*60];
      for (int a=0;a<60;a++){ float v=imk[a]; float2 p=ph[(m*a)%60]; sr+=v*p.x; si-=v*p.y; }
      G[(k<<4)+m]=make_float2(sr,si);
    }
    __syncthreads();
    int off=t;
    int l=0; while((l+1)*(l+1)<=off) l++;
    int mm=off-l*l; int m=mm-l; int am = m<0?-m:m;
    float xr=0.f, xi=0.f;
    for (int k=0;k<60;k++){
      float w=wd_s2[(l*60+k)*31+mm];
      float2 g=G[(k<<4)+am];
      float gi = (m<0)? -g.y : g.y;
      xr += w*g.x; xi += w*gi;
    }
    X[b*256+off]=make_float2(xr,xi);
  } else if (bid<108){
    int f=bid-8;
    __shared__ float wv[60];
    __shared__ float2 W[16];
    for (int p=t;p<60;p+=256) wv[p]=w_s2[f*60+p];
    __syncthreads();
    if (t<16){
      float sr=0.f, si=0.f;
      for (int p=0;p<60;p++){ float2 p2=ph60[(t*p)%60]; sr+=wv[p]*p2.x; si-=wv[p]*p2.y; }
      W[t]=make_float2(sr/60.f, si/60.f);
    }
    __syncthreads();
    {
      int off=t;
      int l=0; while((l+1)*(l+1)<=off) l++;
      int mm=off-l*l; int m=mm-l; int am=m<0?-m:m;
      float dh=Df[l*961 + mm*(2*l+1) + l];
      float2 wm=W[am];
      float wi = (m>=0)? -wm.y : wm.y;
      YC[f*256+off]=make_float2(dh*wm.x, dh*wi);
    }
  } else {
    int tid=(bid-108)*256+t;
    if (tid<10000){
      int i=tid/100, o=tid-i*100;
      float wv2[32];
      for (int p=0;p<32;p++) wv2[p]=w_so3[(i*100+o)*32+p];
      for (int m=0;m<10;m++){
        float sr=0.f, si=0.f;
        for (int p=0;p<32;p++){ float2 p2=ph32g[(m*p)&31]; sr+=wv2[p]*p2.x; si-=wv2[p]*p2.y; }
        WH2[((size_t)m*100+i)*100+o]=make_float2(sr/32.f, si/32.f);
      }
    }
  }
}

// ---------------- u compact (ns>=0): writes PADDED layout [b,k][c*33+a] ----------------
__global__ void k_u(const float2* X, const float* dif16, const float2* ph32g, float2* u){
  int bid=blockIdx.x;
  int l, k, ns0, ns1;
  if (bid < 256){ l = bid>>5; k = bid&31; ns0=0; ns1=l+1; }
  else {
    int q=bid-256; l = 8 + (q>>6); int half=(q>>5)&1; k=q&31;
    int mid=(l+2)>>1;
    ns0 = half? mid : 0; ns1 = half? (l+1) : mid;
  }
  int n=2*l+1;
  __shared__ float d[961];
  __shared__ float2 Xs[8][31];
  __shared__ float2 ph[32];
  int t=threadIdx.x;
  if (t<32) ph[t]=ph32g[t];
  for (int i=t;i<n*n;i+=256) d[i]=dif16[(size_t)(l*32+k)*961+i];
  if (t<8*n){ int b=t/n, mm=t-b*n; Xs[b][mm]=X[b*256+l*l+mm]; }
  __syncthreads();
  int b=t>>5, a=t&31;
  float2* up = u + (size_t)(b*32+k)*4488 + a;
  for (int ns=ns0; ns<ns1; ++ns){
    float ar=0.f, ai=0.f;
    int nn = ns + l;
    for (int mm=0; mm<n; ++mm){
      float2 x=Xs[b][mm];
      float2 p=ph[((mm-l)*a)&31];
      float pr=x.x*p.x-x.y*p.y, pi=x.x*p.y+x.y*p.x;
      float dv=d[mm*n+nn];
      ar += dv*pr; ai += dv*pi;
    }
    up[(size_t)(c_T[l]+ns)*33]=make_float2(ar,ai);
  }
}

// ---------------- big inverse transform v9 (R17-proven): LDS-staged u2, g<->16-g folded stage C
#define KH_F 8
__global__ __launch_bounds__(512,4) void k_h(const float2* __restrict__ u, const float2* __restrict__ YC,
                                             float* __restrict__ h, double2* __restrict__ part){
  int bid=blockIdx.x;
  int fg = bid % 13; int rem = bid/13; int kp = rem & 15; int b = rem >> 4;
  int k0 = kp*2;
  int f0 = fg*KH_F; int F_act = (f0+KH_F<=100)? KH_F : (100-f0);

  __shared__ alignas(16) float2 u2[2][4488];
  __shared__ float2 ysc[KH_F*136];
  int t=threadIdx.x;

  {
    const float4* gs = (const float4*)(u + (size_t)(b*32+k0)*4488);
    float4* ls = (float4*)&u2[0][0];
    for (int j=t; j<4488; j+=512) ls[j]=gs[j];
  }
  for (int i=t; i<KH_F*136; i+=512){
    int fi=i/136, c=i-fi*136;
    float2 y=make_float2(0.f,0.f);
    if (fi<F_act){
      int l=l_from_T(c); int ns=c-c_T[l];
      y=YC[(size_t)(f0+fi)*256 + l*l+l+ns];
    }
    ysc[i]=y;
  }
  __syncthreads();

  int kk = t>>8, tt = t&255;
  float* vbase = (float*)&u2[kk][0];

  {
    int ns = tt>>4; int sub = tt&15; int ft = sub>>3; int at = sub&7;
    int a0 = at*4;
    const float2* uk = u2[kk];
    float ar[16], ai[16];
    #pragma unroll
    for (int q=0;q<16;q++){ ar[q]=0.f; ai[q]=0.f; }
    for (int l=ns; l<16; ++l){
      int c = c_T[l]+ns;
      float2 y0=ysc[(ft*4+0)*136+c];
      float2 y1=ysc[(ft*4+1)*136+c];
      float2 y2=ysc[(ft*4+2)*136+c];
      float2 y3=ysc[(ft*4+3)*136+c];
      float2 U0=uk[c*33+a0+0];
      float2 U1=uk[c*33+a0+1];
      float2 U2=uk[c*33+a0+2];
      float2 U3=uk[c*33+a0+3];
      #define CM(j,Y,i_,Ui) \
        ar[(j)*4+(i_)] += (Y).x*(Ui).x - (Y).y*(Ui).y; \
        ai[(j)*4+(i_)] += (Y).x*(Ui).y + (Y).y*(Ui).x;
      CM(0,y0,0,U0) CM(0,y0,1,U1) CM(0,y0,2,U2) CM(0,y0,3,U3)
      CM(1,y1,0,U0) CM(1,y1,1,U1) CM(1,y1,2,U2) CM(1,y1,3,U3)
      CM(2,y2,0,U0) CM(2,y2,1,U1) CM(2,y2,2,U2) CM(2,y2,3,U3)
      CM(3,y3,0,U0) CM(3,y3,1,U1) CM(3,y3,2,U2) CM(3,y3,3,U3)
      #undef CM
    }
    __syncthreads();
    float* vr = vbase;
    float* vi = vbase + 4352;
    #pragma unroll
    for (int j=0;j<4;j++){
      #pragma unroll
      for (int i=0;i<4;i++){
        int fi=ft*4+j, a=a0+i;
        vr[(fi*32+a)*17+ns]=ar[j*4+i];
        vi[(fi*32+a)*17+ns]=ai[j*4+i];
      }
    }
  }
  __syncthreads();

  {
    const float* vr = vbase;
    const float* vi = vbase + 4352;
    int fi=tt>>5, a=tt&31;
    float xr[16], xi[16];
    #pragma unroll
    for (int ns=0;ns<16;ns++){ xr[ns]=vr[(fi*32+a)*17+ns]; xi[ns]=vi[(fi*32+a)*17+ns]; }
    float vr0 = xr[0];
    bool wr = (fi<F_act);
    float* hp = h + ((size_t)(b*100+f0+fi)*32 + (k0+kk))*1024 + a;
    float sf=0.f, qf=0.f;
    #define EMIT(gidx, hv) { float hv_=(hv); if(wr) hp[(gidx)*32]=hv_; sf+=hv_; qf+=hv_*hv_; }
    {
      float se=0.f, so=0.f;
      #pragma unroll
      for (int ns=0; ns<16; ++ns){ if (ns&1) so+=xr[ns]; else se+=xr[ns]; }
      EMIT(0,  2.f*(se+so)-vr0);
      EMIT(16, 2.f*(se-so)-vr0);
    }
    {
      float se=0.f, so=0.f;
      #pragma unroll
      for (int ns=0; ns<16; ++ns){
        const int idx=(ns*8)&31;
        float term = xr[ns]*CS32[idx] - xi[ns]*SN32[idx];
        if (ns&1) so+=term; else se+=term;
      }
      EMIT(8,  2.f*(se+so)-vr0);
      EMIT(24, 2.f*(se-so)-vr0);
    }
    #pragma unroll
    for (int g=1; g<8; ++g){
      float SAe=0.f, SBe=0.f, SAo=0.f, SBo=0.f;
      #pragma unroll
      for (int ns=0; ns<16; ++ns){
        const int idx=(ns*g)&31;
        float A = xr[ns]*CS32[idx];
        float B = xi[ns]*SN32[idx];
        if (ns&1){ SAo+=A; SBo+=B; } else { SAe+=A; SBe+=B; }
      }
      float se1=SAe-SBe, so1=SAo-SBo;
      float se2=SAe+SBe, so2=-(SAo+SBo);
      EMIT(g,      2.f*(se1+so1)-vr0);
      EMIT(g+16,   2.f*(se1-so1)-vr0);
      EMIT(16-g,   2.f*(se2+so2)-vr0);
      EMIT(32-g,   2.f*(se2-so2)-vr0);
    }
    #undef EMIT
    for (int d=16; d>0; d>>=1){ sf += __shfl_down(sf, d, 32); qf += __shfl_down(qf, d, 32); }
    if (a==0 && fi<F_act){
      atomicAdd(&part[b*100+f0+fi].x, (double)sf);
      atomicAdd(&part[b*100+f0+fi].y, (double)qf);
    }
  }
}

// ---------------- BN scale/shift from partials; self-zeroes part ----------------
__global__ void k_bn2(const double2* __restrict__ partial, int per, const float* g, const float* bb,
                      float* scale, float* shift, double2* partial_w){
  int f=blockIdx.x*64+threadIdx.x;
  if (f>=100) return;
  double s=0.0, q=0.0;
  for (int b=0;b<8;b++){ double2 v=partial[b*100+f]; s+=v.x; q+=v.y; }
  for (int b=0;b<8;b++){ partial_w[b*100+f]=make_double2(0.0,0.0); }
  double cnt=8.0*(double)per;
  double mu=s/cnt, var=q/cnt-mu*mu;
  double sc=(double)g[f]/sqrt(var+1e-5);
  scale[f]=(float)sc; shift[f]=(float)((double)bb[f]-mu*sc);
}

// ---------------- k_g v3b: block = (bc, k-quad), 256 thr = 4 waves ----------------
template<int M0>
__device__ __forceinline__ void alpha_dft(const float* __restrict__ yk, float2* __restrict__ tdst, int g){
  float ax0=0.f,ay0=0.f, ax1=0.f,ay1=0.f, ax2=0.f,ay2=0.f, ax3=0.f,ay3=0.f, ax4=0.f,ay4=0.f;
  #pragma unroll
  for (int a=0;a<16;a++){
    float ya=yk[a], yb=yk[a+16];
    float yp=ya+yb, ym=ya-yb;
    #define AM(mi, AX, AY) { \
      const int m_ = M0+mi; \
      const int idx_ = (m_*a)&31; \
      float v_ = (m_&1)? ym : yp; \
      AX += v_*CS32[idx_]; \
      AY -= v_*SN32[idx_]; }
    AM(0,ax0,ay0) AM(1,ax1,ay1) AM(2,ax2,ay2) AM(3,ax3,ay3) AM(4,ax4,ay4)
    #undef AM
  }
  tdst[(M0+0)*33+g]=make_float2(ax0,ay0);
  tdst[(M0+1)*33+g]=make_float2(ax1,ay1);
  tdst[(M0+2)*33+g]=make_float2(ax2,ay2);
  tdst[(M0+3)*33+g]=make_float2(ax3,ay3);
  tdst[(M0+4)*33+g]=make_float2(ax4,ay4);
}

__global__ __launch_bounds__(256) void k_g(const float* __restrict__ h, const float* __restrict__ scale,
                                           const float* __restrict__ shift, const float2* __restrict__ ph32g,
                                           float2* __restrict__ G){
  int bid=blockIdx.x; int kq=bid&7; int bc=bid>>3; int c=bc%100;
  int k0 = kq*4;
  __shared__ float y[4][32*33];
  __shared__ float2 tsc[4][10*33];
  int t=threadIdx.x;
  float sc=scale[c], sh=shift[c];
  {
    const float4* h4 = (const float4*)(h + (size_t)bc*32768 + (size_t)k0*1024);
    for (int i=t;i<1024;i+=256){
      float4 v=h4[i];
      int base=i<<2;
      int kk=base>>10, idx=base&1023, g=idx>>5, a=idx&31;
      float* yw=&y[kk][g*33+a];
      yw[0]=fmaxf(v.x*sc+sh, 0.f);
      yw[1]=fmaxf(v.y*sc+sh, 0.f);
      yw[2]=fmaxf(v.z*sc+sh, 0.f);
      yw[3]=fmaxf(v.w*sc+sh, 0.f);
    }
  }
  __syncthreads();
  int wid=t>>6, lane=t&63;
  {
    int mh=wid&1, kh=wid>>1;
    int kk=kh*2+(lane>>5), g=lane&31;
    const float* yk=&y[kk][g*33];
    if (mh==0) alpha_dft<0>(yk, tsc[kk], g);
    else       alpha_dft<5>(yk, tsc[kk], g);
  }
  __syncthreads();
  if (lane<50){
    int kk=wid;
    int mrow=lane/5, p=lane%5;
    int sa=2*p+1, sb=(p==4)? 0 : 2*p+2;
    const float2* tk=&tsc[kk][mrow*33];
    float2 stA=ph32g[sa];
    float2 stB=ph32g[sb];
    float Aa=0.f,Ba=0.f,Ca=0.f,Da=0.f, Ab=0.f,Bb=0.f,Cb=0.f,Db=0.f;
    #pragma unroll
    for (int half=0; half<2; ++half){
      int ea=(sa*half)&3, eb=(sb*half)&3;
      float2 qa=make_float2(ea==0?1.f:(ea==2?-1.f:0.f), ea==1?1.f:(ea==3?-1.f:0.f));
      float2 qb=make_float2(eb==0?1.f:(eb==2?-1.f:0.f), eb==1?1.f:(eb==3?-1.f:0.f));
      #pragma unroll
      for (int g8=0; g8<8; ++g8){
        int g=half*8+g8;
        float2 ta=tk[g], tb=tk[g+16];
        float tpx=ta.x+tb.x, tpy=ta.y+tb.y;
        float tmx=ta.x-tb.x, tmy=ta.y-tb.y;
        Aa += tmx*qa.x; Ba += tmy*qa.y; Ca += tmy*qa.x; Da += tmx*qa.y;
        Ab += tpx*qb.x; Bb += tpy*qb.y; Cb += tpy*qb.x; Db += tpx*qb.y;
        float nax=qa.x*stA.x - qa.y*stA.y, nay=qa.x*stA.y + qa.y*stA.x; qa=make_float2(nax,nay);
        float nbx=qb.x*stB.x - qb.y*stB.y, nby=qb.x*stB.y + qb.y*stB.x; qb=make_float2(nbx,nby);
      }
    }
    float2* Gp = G + (size_t)(bc*32 + k0+kk)*190 + mrow*19;
    Gp[9+sa]=make_float2(Aa+Ba, Ca-Da);
    Gp[9-sa]=make_float2(Aa-Ba, Ca+Da);
    Gp[9+sb]=make_float2(Ab+Bb, Cb-Db);
    Gp[9-sb]=make_float2(Ab-Bb, Cb+Db);
  }
}

// ---------------- k_x2 (R8/R19-proven flat, RESTORED from k_xa): X2h = sum_k wd16 * G ----------------
__global__ void k_x2(const float2* __restrict__ G, const float* __restrict__ wd16, float2* __restrict__ X2){
  int tid=blockIdx.x*256+threadIdx.x;
  if (tid>=800*715) return;
  int bc=tid/715, i=tid-bc*715;
  int l=l_from_offH(i); int rem=i-c_offH[l]; int n=2*l+1;
  int m=rem/n, kk2=rem-m*n; int ng=kk2-l;
  int j = m*19+(ng+9);
  const float2* Gp = G + (size_t)bc*32*190 + j;
  const float*  wp = wd16 + (size_t)l*32*361 + (m+l)*n + kk2;
  float ar=0.f, ai=0.f;
  #pragma unroll 8
  for (int k=0;k<32;k++){
    float2 gv=Gp[(size_t)k*190];
    float  wv=wp[(size_t)k*361];
    ar += wv*gv.x; ai += wv*gv.y;
  }
  X2[tid]=make_float2(ar, ai);
}

// ---------------- k_A (R19-proven flat, RESTORED): 2-way unrolled complex dot over kk ----------------
__global__ void k_A(const float2* __restrict__ X2, const float* __restrict__ Df, float2* __restrict__ A){
  int tid = blockIdx.x*256 + threadIdx.x;
  if (tid >= 800*715) return;
  int bi = tid/715, off = tid - bi*715;
  int l = l_from_offH(off); int rem = off - c_offH[l]; int n = 2*l+1;
  int m = rem/n, nn = rem - m*n;
  const float2* Xp = X2 + (size_t)bi*715 + c_offH[l] + m*n;
  const float* Dp = Df + l*961 + nn*n;
  float ar=0.f, ai=0.f;
  float br=0.f, bis=0.f;
  int kk=0;
  for (; kk+1<n; kk+=2){
    float2 x0 = Xp[kk];   float d0 = Dp[kk];
    float2 x1 = Xp[kk+1]; float d1 = Dp[kk+1];
    ar += x0.x*d0; ai += x0.y*d0;
    br += x1.x*d1; bis += x1.y*d1;
  }
  if (kk<n){ float2 x = Xp[kk]; float dv = Dp[kk]; ar += x.x*dv; ai += x.y*dv; }
  A[tid] = make_float2(ar+br, ai+bis);
}

// ---------------- Z2 (half rows): Z2h = sum_i A * conj(What2) ----------------
__global__ void k_z2(const float2* A, const float2* WH2, float2* Z2){
  int bid=blockIdx.x; int b=bid&7; int r=bid>>3;
  int l=l_from_sq(r); int nn=r-l*l; int n=2*l+1; int ns=nn-l;
  int nrow=l+1;
  __shared__ float2 As[100*10];
  int t=threadIdx.x;
  for (int idx=t; idx<100*nrow; idx+=256){
    int i=idx/nrow, m=idx-i*nrow;
    As[idx]=A[(size_t)(b*100+i)*715 + c_offH[l] + m*n + nn];
  }
  __syncthreads();
  int mabs = ns<0?-ns:ns;
  const float2* Wp = WH2 + (size_t)mabs*10000;
  float sgn = (ns>=0)? -1.f : 1.f;
  for (int idx=t; idx<100*nrow; idx+=256){
    int o=idx/nrow, m=idx-o*nrow;
    float zr=0.f, zi=0.f;
    #pragma unroll 4
    for (int i=0;i<100;i++){
      float2 a=As[i*nrow+m];
      float2 w=Wp[i*100+o]; float wr=w.x, wi=sgn*w.y;
      zr += a.x*wr - a.y*wi;
      zi += a.x*wi + a.y*wr;
    }
    Z2[(size_t)(b*100+o)*715 + c_offH[l] + m*n + nn]=make_float2(zr,zi);
  }
}

// ---------------- fused SO3 IFFT at b=10 v6: k-PAIRED blocks (256 thr) ----------------
__global__ __launch_bounds__(256) void k_ifft10(const float2* __restrict__ Z2, const float* __restrict__ dif10t,
                                                const float2* __restrict__ ph20g, float* __restrict__ h2,
                                                double2* __restrict__ part){
  int bid=blockIdx.x; int bf=bid/10, kp=bid-10*bf;
  int k0=kp*2;
  __shared__ float2 Zs[715];
  __shared__ float2 M[2][190];
  __shared__ float2 T[2][200];
  __shared__ float2 ph[20];
  __shared__ float rs[256], rq[256];
  int t=threadIdx.x;
  if (t<20) ph[t]=ph20g[t];
  const float2* Zp = Z2 + (size_t)bf*715;
  for (int i=t;i<715;i+=256) Zs[i]=Zp[i];
  __syncthreads();
  {
    int kk = t>>7, tt = t&127;
    int k = k0+kk;
    for (int i=tt;i<190;i+=128){
      int ms=i/19, n9=i-ms*19; int nsg=n9-9;
      int a2=nsg<0?-nsg:nsg; int l0 = ms>a2?ms:a2;
      float mr=0.f, mi=0.f;
      const float* dp = dif10t + (size_t)k*1900 + i;
      for (int l=l0;l<10;l++){
        float dv=dp[l*190];
        float2 z=Zs[c_offH[l] + ms*(2*l+1) + nsg + l];
        mr += dv*z.x; mi += dv*z.y;
      }
      M[kk][i]=make_float2(mr,mi);
    }
  }
  __syncthreads();
  if (t<200){
    int kk=t/100, j=t-100*kk;
    int g=j/5, ms0=(j%5)*2;
    const float2* Mp0=&M[kk][ms0*19];
    const float2* Mp1=Mp0+19;
    float2 stp=ph[g];
    float2 p=ph[(11*g)%20];
    float tr0=0.f,ti0=0.f,tr1=0.f,ti1=0.f;
    #pragma unroll
    for (int n9=0;n9<19;n9++){
      float2 m0=Mp0[n9], m1=Mp1[n9];
      tr0 += m0.x*p.x - m0.y*p.y;
      ti0 += m0.x*p.y + m0.y*p.x;
      tr1 += m1.x*p.x - m1.y*p.y;
      ti1 += m1.x*p.y + m1.y*p.x;
      float nx=p.x*stp.x - p.y*stp.y, ny=p.x*stp.y + p.y*stp.x;
      p=make_float2(nx,ny);
    }
    T[kk][ms0*20+g]=make_float2(tr0,ti0);
    T[kk][(ms0+1)*20+g]=make_float2(tr1,ti1);
  }
  __syncthreads();
  float sf=0.f, qf=0.f;
  if (t<200){
    int kk=t/100, j=t-100*kk;
    int a=j/5, g0=(j%5)*4;
    const float2* Tk=&T[kk][0];
    float acc0=Tk[g0].x, acc1=Tk[g0+1].x, acc2=Tk[g0+2].x, acc3=Tk[g0+3].x;
    float2 stp=ph[a];
    float2 p=stp;
    #pragma unroll
    for (int ms=1; ms<10; ++ms){
      const float2* Tp=&Tk[ms*20+g0];
      float2 t0=Tp[0], t1=Tp[1], t2=Tp[2], t3=Tp[3];
      acc0 += 2.f*(t0.x*p.x - t0.y*p.y);
      acc1 += 2.f*(t1.x*p.x - t1.y*p.y);
      acc2 += 2.f*(t2.x*p.x - t2.y*p.y);
      acc3 += 2.f*(t3.x*p.x - t3.y*p.y);
      float nx=p.x*stp.x - p.y*stp.y, ny=p.x*stp.y + p.y*stp.x;
      p=make_float2(nx,ny);
    }
    float* hp = h2 + (size_t)bf*8000 + (k0+kk)*400 + a*20 + g0;
    *(float4*)hp = make_float4(acc0,acc1,acc2,acc3);
    sf = acc0+acc1+acc2+acc3;
    qf = acc0*acc0+acc1*acc1+acc2*acc2+acc3*acc3;
  }
  rs[t]=sf; rq[t]=qf; __syncthreads();
  for (int w=128;w>0;w>>=1){ if(t<w){rs[t]+=rs[t+w]; rq[t]+=rq[t+w];} __syncthreads(); }
  if (t==0){
    atomicAdd(&part[bf].x, (double)rs[0]);
    atomicAdd(&part[bf].y, (double)rq[0]);
  }
}

// ---------------- BN2+ReLU + SO3 integrate -> feat ----------------
__global__ void k_integrate(const float* h2, const float* scale, const float* shift, const float* qw10, float* feat){
  int bf=blockIdx.x; int f=bf%100; int t=threadIdx.x;
  float sc=scale[f], sh=shift[f];
  const float4* p4=(const float4*)(h2+(size_t)bf*8000);
  float s=0.f;
  for (int i4=t;i4<2000;i4+=256){
    float4 v=p4[i4];
    float qw=qw10[i4/100];
    float r0=fmaxf(v.x*sc+sh,0.f);
    float r1=fmaxf(v.y*sc+sh,0.f);
    float r2=fmaxf(v.z*sc+sh,0.f);
    float r3=fmaxf(v.w*sc+sh,0.f);
    s += (r0+r1+r2+r3)*qw;
  }
  __shared__ float r[256];
  r[t]=s; __syncthreads();
  for (int w=128;w>0;w>>=1){ if(t<w) r[t]+=r[t+w]; __syncthreads(); }
  if (t==0){
    float c=(float)((2.0*M_PI/20.0)*(2.0*M_PI/20.0));
    feat[bf]=r[0]*c;
  }
}

// ---------------- final linear ----------------
__global__ void k_logits(const float* feat, const float* lw, const float* lb, float* out){
  int t=blockIdx.x*64+threadIdx.x;
  if (t>=320) return;
  int b=t/40, c=t-40*b;
  float s=lb[c];
  for (int f=0;f<100;f++) s += feat[b*100+f]*lw[f*40+c];
  out[t]=s;
}

extern "C" void kernel_launch(void* const* d_in, const int* in_sizes, int n_in,
                              void* d_out, int out_size, void* d_ws, size_t ws_size,
                              hipStream_t stream){
  (void)in_sizes; (void)n_in; (void)out_size; (void)ws_size;
  const float* x    = (const float*)d_in[0];
  const float* w_s2 = (const float*)d_in[1];
  const float* bn1g = (const float*)d_in[3];
  const float* bn1b = (const float*)d_in[4];
  const float* w_so3= (const float*)d_in[5];
  const float* bn2g = (const float*)d_in[7];
  const float* bn2b = (const float*)d_in[8];
  const float* linw = (const float*)d_in[9];
  const float* linb = (const float*)d_in[10];
  float* out = (float*)d_out;

  char* base=(char*)d_ws; size_t off=0;
  auto alloc=[&](size_t bytes)->void*{ void* p=base+off; off=(off+bytes+255)&~(size_t)255; return p; };
  double* Dd   = (double*)alloc((size_t)16*961*8);
  float*  Df   = (float*) alloc((size_t)16*961*4);
  float*  qw30 = (float*) alloc(256);
  float*  qw16 = (float*) alloc(256);
  float*  qw10 = (float*) alloc(256);
  float2* ph60 = (float2*)alloc(512);
  float2* ph32 = (float2*)alloc(256);
  float2* ph20 = (float2*)alloc(256);
  float*  wd_s2= (float*) alloc((size_t)16*60*31*4);
  float*  dif16= (float*) alloc((size_t)16*32*961*4);
  float*  wd16 = (float*) alloc((size_t)10*32*361*4);
  float*  dif10t=(float*) alloc((size_t)20*10*190*4);
  float*  img  = (float*) alloc((size_t)8*3600*4);
  float2* X    = (float2*)alloc((size_t)8*256*8);
  float2* YC   = (float2*)alloc((size_t)100*256*8);
  float2* u    = (float2*)alloc((size_t)8*32*4488*8);
  float*  h    = (float*) alloc((size_t)8*100*32768*4);
  float*  sc1  = (float*) alloc(512);
  float*  sh1  = (float*) alloc(512);
  float2* Gbuf = (float2*)alloc((size_t)800*32*190*8);
  float2* X2   = (float2*)alloc((size_t)800*715*8);
  float2* WH2  = (float2*)alloc((size_t)10*100*100*8);
  float2* A    = (float2*)alloc((size_t)800*715*8);
  float2* Z2   = (float2*)alloc((size_t)800*715*8);
  float*  h2   = (float*) alloc((size_t)8*100*8000*4);
  float*  sc2  = (float*) alloc(512);
  float*  sh2  = (float*) alloc(512);
  float*  feat = (float*) alloc(4096);
  double2* part= (double2*)alloc((size_t)800*16);
  unsigned long long* tflag = (unsigned long long*)alloc(256);

  k_dq<<<17, 1024, 0, stream>>>(Dd, Df, qw30, qw16, qw10, ph32, ph20, ph60, tflag);
  k_tables<<<1672, 256, 0, stream>>>(Dd, qw30, qw16, qw10, wd_s2, dif16, wd16, dif10t, tflag);
  k_prep<<<32, 256, 0, stream>>>(tflag, img, part);
  k_project<<<32, 256, 0, stream>>>(x, img);
  k_front<<<148, 256, 0, stream>>>(img, ph60, wd_s2, X, w_s2, Df, YC, w_so3, ph32, WH2);
  k_u<<<768, 256, 0, stream>>>(X, dif16, ph32, u);
  k_h<<<8*16*13, 512, 0, stream>>>(u, YC, h, part);
  k_bn2<<<2, 64, 0, stream>>>(part, 32768, bn1g, bn1b, sc1, sh1, part);
  k_g<<<800*8, 256, 0, stream>>>(h, sc1, sh1, ph32, Gbuf);
  k_x2<<<(800*715+255)/256, 256, 0, stream>>>(Gbuf, wd16, X2);
  k_A<<<(800*715+255)/256, 256, 0, stream>>>(X2, Df, A);
  k_z2<<<800, 256, 0, stream>>>(A, WH2, Z2);
  k_ifft10<<<8000, 256, 0, stream>>>(Z2, dif10t, ph20, h2, part);
  k_bn2<<<2, 64, 0, stream>>>(part, 8000, bn2g, bn2b, sc2, sh2, part);
  k_integrate<<<800, 256, 0, stream>>>(h2, sc2, sh2, qw10, feat);
  k_logits<<<5, 64, 0, stream>>>(feat, linw, linb, out);
}

// Round 22
// 395.076 us; speedup vs baseline: 1.0326x; 1.0172x over previous
//
#include <hip/hip_runtime.h>
#include <math.h>

#ifndef M_PI
#define M_PI 3.14159265358979323846
#endif

#define TBL_MAGIC 0x5EED5EEDCAFEF00EULL

__device__ const int c_off2[11] = {0,1,10,35,84,165,286,455,680,969,1330};
__device__ const int c_offH[11] = {0,1,7,22,50,95,161,252,372,525,715};
__device__ const int c_T[17] = {0,1,3,6,10,15,21,28,36,45,55,66,78,91,105,120,136};

__device__ constexpr float CS32[32] = {
  1.0f, 0.98078528f, 0.92387953f, 0.83146961f, 0.70710678f, 0.55557023f, 0.38268343f, 0.19509032f,
  0.0f,-0.19509032f,-0.38268343f,-0.55557023f,-0.70710678f,-0.83146961f,-0.92387953f,-0.98078528f,
 -1.0f,-0.98078528f,-0.92387953f,-0.83146961f,-0.70710678f,-0.55557023f,-0.38268343f,-0.19509032f,
  0.0f, 0.19509032f, 0.38268343f, 0.55557023f, 0.70710678f, 0.83146961f, 0.92387953f, 0.98078528f};
__device__ constexpr float SN32[32] = {
  0.0f, 0.19509032f, 0.38268343f, 0.55557023f, 0.70710678f, 0.83146961f, 0.92387953f, 0.98078528f,
  1.0f, 0.98078528f, 0.92387953f, 0.83146961f, 0.70710678f, 0.55557023f, 0.38268343f, 0.19509032f,
  0.0f,-0.19509032f,-0.38268343f,-0.55557023f,-0.70710678f,-0.83146961f,-0.92387953f,-0.98078528f,
 -1.0f,-0.98078528f,-0.92387953f,-0.83146961f,-0.70710678f,-0.55557023f,-0.38268343f,-0.19509032f};

__device__ __forceinline__ int l_from_sq(int off){ int l=0; while((l+1)*(l+1)<=off) l++; return l; }
__device__ __forceinline__ int l_from_offH(int off){ int l=0; while(c_offH[l+1]<=off) l++; return l; }
__device__ __forceinline__ int l_from_T(int c){ int l=0; while(c_T[l+1]<=c) l++; return l; }

// ---------------- k_dq: fused Wigner Delta (blocks 0-15) + qw/phase tables (block 16) ----------------
__global__ void k_dq(double* Dd, float* Df, float* qw30, float* qw16, float* qw10,
                     float2* ph32, float2* ph20, float2* ph60,
                     const unsigned long long* __restrict__ tflag){
  if (tflag[0]==TBL_MAGIC) return;
  if (blockIdx.x==16){
    int t=threadIdx.x;
    if (t<60){
      double beta=M_PI*(2*t+1)/120.0, s=0.0;
      for (int j=0;j<30;j++) s += sin((double)(2*t+1)*(2*j+1)*M_PI/120.0)/(double)(2*j+1);
      qw30[t]=(float)((2.0/30.0)*sin(beta)*s);
      double a=2.0*M_PI*t/60.0; ph60[t]=make_float2((float)cos(a),(float)sin(a));
    }
    if (t<32){
      double beta=M_PI*(2*t+1)/64.0, s=0.0;
      for (int j=0;j<16;j++) s += sin((double)(2*t+1)*(2*j+1)*M_PI/64.0)/(double)(2*j+1);
      qw16[t]=(float)((2.0/16.0)*sin(beta)*s);
      double a=2.0*M_PI*t/32.0; ph32[t]=make_float2((float)cos(a),(float)sin(a));
    }
    if (t<20){
      double beta=M_PI*(2*t+1)/40.0, s=0.0;
      for (int j=0;j<10;j++) s += sin((double)(2*t+1)*(2*j+1)*M_PI/40.0)/(double)(2*j+1);
      qw10[t]=(float)((2.0/10.0)*sin(beta)*s);
      double a=2.0*M_PI*t/20.0; ph20[t]=make_float2((float)cos(a),(float)sin(a));
    }
    return;
  }
  int l = blockIdx.x; int n = 2*l+1; int n2=n*n;
  __shared__ double A[961], T[961], Tm[961];
  for (int idx=threadIdx.x; idx<n2; idx+=1024){
    int r=idx/n, c=idx-r*n;
    double v=0.0;
    if (r==c+1){ double m=(double)(c-l); v = -0.5*sqrt((double)l*(l+1)-m*(m+1)); }
    else if (c==r+1){ double m=(double)(r-l); v = 0.5*sqrt((double)l*(l+1)-m*(m+1)); }
    A[idx] = v*(M_PI*0.5/128.0);
    T[idx] = (r==c)?1.0:0.0;
  }
  __syncthreads();
  for (int j=14; j>=1; --j){
    for (int idx=threadIdx.x; idx<n2; idx+=1024){
      int r=idx/n, c=idx-r*n; double acc=0.0;
      if (r>0)   acc += A[r*n+(r-1)]*T[(r-1)*n+c];
      if (r<n-1) acc += A[r*n+(r+1)]*T[(r+1)*n+c];
      Tm[idx]=acc;
    }
    __syncthreads();
    for (int idx=threadIdx.x; idx<n2; idx+=1024){
      int r=idx/n, c=idx-r*n;
      T[idx] = ((r==c)?1.0:0.0) + Tm[idx]/(double)j;
    }
    __syncthreads();
  }
  for (int s=0; s<7; ++s){
    for (int idx=threadIdx.x; idx<n2; idx+=1024){
      int r=idx/n, c=idx-r*n; double acc=0.0;
      for (int q=0;q<n;q++) acc += T[r*n+q]*T[q*n+c];
      Tm[idx]=acc;
    }
    __syncthreads();
    for (int idx=threadIdx.x; idx<n2; idx+=1024) T[idx]=Tm[idx];
    __syncthreads();
  }
  for (int idx=threadIdx.x; idx<n2; idx+=1024){ Dd[l*961+idx]=T[idx]; Df[l*961+idx]=(float)T[idx]; }
}

// ---------------- beta-grid Wigner tables from Delta ----------------
__global__ void k_tables(const double* Dd, const float* qw30, const float* qw16, const float* qw10,
                         float* wd_s2, float* dif16, float* wd16, float* dif10t,
                         const unsigned long long* __restrict__ tflag){
  if (tflag[0]==TBL_MAGIC) return;
  int bid=blockIdx.x;
  __shared__ double cc[32], ss[32];
  int l,k,mode; double beta;
  if (bid<960){ mode=0; l=bid/60; k=bid%60; beta=M_PI*(2*k+1)/120.0; }
  else if (bid<1472){ mode=1; int q=bid-960; l=q/32; k=q%32; beta=M_PI*(2*k+1)/64.0; }
  else { mode=2; int q=bid-1472; l=q/20; k=q%20; beta=M_PI*(2*k+1)/40.0; }
  int n=2*l+1;
  for (int kk=threadIdx.x; kk<=l; kk+=256){ cc[kk]=cos(kk*beta); ss[kk]=sin(kk*beta); }
  __syncthreads();
  const double* D = Dd + l*961;
  if (mode==0){
    for (int mm=threadIdx.x; mm<n; mm+=256){
      int m=mm-l; int p=((m)%4+4)%4; double s=0.0;
      for (int kk=-l; kk<=l; ++kk){
        int ak = kk<0?-kk:kk;
        double c=cc[ak], sn=(kk<0)?-ss[ak]:ss[ak];
        double f=(p==0)?c:(p==1)?sn:(p==2)?-c:-sn;
        s += D[(kk+l)*n+mm]*D[(kk+l)*n+l]*f;
      }
      wd_s2[(l*60+k)*31+mm] = (float)(s*(double)qw30[k]*(2.0*M_PI/60.0));
    }
  } else if (mode==1){
    for (int idx=threadIdx.x; idx<n*n; idx+=256){
      int mm=idx/n, nn=idx-mm*n; int m=mm-l, nb=nn-l;
      int p=((m-nb)%4+4)%4; double s=0.0;
      for (int kk=-l; kk<=l; ++kk){
        int ak = kk<0?-kk:kk;
        double c=cc[ak], sn=(kk<0)?-ss[ak]:ss[ak];
        double f=(p==0)?c:(p==1)?sn:(p==2)?-c:-sn;
        s += D[(kk+l)*n+mm]*D[(kk+l)*n+nn]*f;
      }
      dif16[(size_t)(l*32+k)*961+idx] = (float)((2*l+1)*s);
      if (l<10) wd16[(size_t)(l*32+k)*361+idx] = (float)(s*(double)qw16[k]*(2.0*M_PI/32.0)*(2.0*M_PI/32.0));
    }
  } else {
    for (int idx=threadIdx.x; idx<n*n; idx+=256){
      int mm=idx/n, nn=idx-mm*n; int m=mm-l, nb=nn-l;
      int p=((m-nb)%4+4)%4; double s=0.0;
      for (int kk=-l; kk<=l; ++kk){
        int ak = kk<0?-kk:kk;
        double c=cc[ak], sn=(kk<0)?-ss[ak]:ss[ak];
        double f=(p==0)?c:(p==1)?sn:(p==2)?-c:-sn;
        s += D[(kk+l)*n+mm]*D[(kk+l)*n+nn]*f;
      }
      if (mm>=l){
        int ms=mm-l, n9=nn-l+9;
        dif10t[((size_t)k*10+l)*190 + ms*19 + n9] = (float)((2*l+1)*s);
      }
    }
  }
}

// ---------------- prep: setflag + zero img/part ----------------
__global__ void k_prep(unsigned long long* tflag, float* img, double2* part){
  int gid = blockIdx.x*256 + threadIdx.x;
  if (gid==0) tflag[0]=TBL_MAGIC;
  for (int i=gid; i<28800; i+=8192) img[i]=0.f;
  for (int i=gid; i<800;   i+=8192) part[i]=make_double2(0.0,0.0);
}

// ---------------- project point cloud to S2 grid (max-scatter) ----------------
__global__ void k_project(const float* x, float* img){
  int tid = blockIdx.x*256+threadIdx.x;
  if (tid>=8192) return;
  int b=tid>>10, n=tid&1023;
  float px=x[(b*3+0)*1024+n], py=x[(b*3+1)*1024+n], pz=x[(b*3+2)*1024+n];
  float r = sqrtf(px*px+py*py+pz*pz);
  float rc = fmaxf(r, 1e-8f);
  float ct = fminf(1.f, fmaxf(-1.f, pz/rc));
  float beta = acosf(ct);
  float alpha = atan2f(py, px);
  const float TWO_PI = 6.283185307179586f;
  alpha = fmodf(alpha, TWO_PI); if (alpha<0.f) alpha += TWO_PI;
  int bi = (int)(beta/3.14159265358979323846f*60.f); bi = min(59, max(0, bi));
  int ai = (int)(alpha/TWO_PI*60.f);                 ai = min(59, max(0, ai));
  atomicMax((int*)&img[(b*60+bi)*60+ai], __float_as_int(r));
}

// ---------------- k_front: fused {s2a+s2b | yc | wh2} via block-range dispatch ----------------
__global__ __launch_bounds__(256) void k_front(const float* __restrict__ img, const float2* __restrict__ ph60,
                                               const float* __restrict__ wd_s2, float2* __restrict__ X,
                                               const float* __restrict__ w_s2, const float* __restrict__ Df,
                                               float2* __restrict__ YC,
                                               const float* __restrict__ w_so3, const float2* __restrict__ ph32g,
                                               float2* __restrict__ WH2){
  int bid=blockIdx.x; int t=threadIdx.x;
  if (bid<8){
    int b=bid;
    __shared__ float im[3600];
    __shared__ float2 G[960];
    __shared__ float2 ph[60];
    if (t<60) ph[t]=ph60[t];
    for (int i=t;i<3600;i+=256) im[i]=img[b*3600+i];
    __syncthreads();
    for (int i=t;i<960;i+=256){
      int k=i>>4, m=i&15;
      float sr=0.f, si=0.f;
      const float* imk=&im[k*60];
      for (int a=0;a<60;a++){ float v=imk[a]; float2 p=ph[(m*a)%60]; sr+=v*p.x; si-=v*p.y; }
      G[(k<<4)+m]=make_float2(sr,si);
    }
    __syncthreads();
    int off=t;
    int l=0; while((l+1)*(l+1)<=off) l++;
    int mm=off-l*l; int m=mm-l; int am = m<0?-m:m;
    float xr=0.f, xi=0.f;
    for (int k=0;k<60;k++){
      float w=wd_s2[(l*60+k)*31+mm];
      float2 g=G[(k<<4)+am];
      float gi = (m<0)? -g.y : g.y;
      xr += w*g.x; xi += w*gi;
    }
    X[b*256+off]=make_float2(xr,xi);
  } else if (bid<108){
    int f=bid-8;
    __shared__ float wv[60];
    __shared__ float2 W[16];
    for (int p=t;p<60;p+=256) wv[p]=w_s2[f*60+p];
    __syncthreads();
    if (t<16){
      float sr=0.f, si=0.f;
      for (int p=0;p<60;p++){ float2 p2=ph60[(t*p)%60]; sr+=wv[p]*p2.x; si-=wv[p]*p2.y; }
      W[t]=make_float2(sr/60.f, si/60.f);
    }
    __syncthreads();
    {
      int off=t;
      int l=0; while((l+1)*(l+1)<=off) l++;
      int mm=off-l*l; int m=mm-l; int am=m<0?-m:m;
      float dh=Df[l*961 + mm*(2*l+1) + l];
      float2 wm=W[am];
      float wi = (m>=0)? -wm.y : wm.y;
      YC[f*256+off]=make_float2(dh*wm.x, dh*wi);
    }
  } else {
    int tid=(bid-108)*256+t;
    if (tid<10000){
      int i=tid/100, o=tid-i*100;
      float wv2[32];
      for (int p=0;p<32;p++) wv2[p]=w_so3[(i*100+o)*32+p];
      for (int m=0;m<10;m++){
        float sr=0.f, si=0.f;
        for (int p=0;p<32;p++){ float2 p2=ph32g[(m*p)&31]; sr+=wv2[p]*p2.x; si-=wv2[p]*p2.y; }
        WH2[((size_t)m*100+i)*100+o]=make_float2(sr/32.f, si/32.f);
      }
    }
  }
}

// ---------------- u compact (ns>=0): writes PADDED layout [b,k][c*33+a] ----------------
__global__ void k_u(const float2* X, const float* dif16, const float2* ph32g, float2* u){
  int bid=blockIdx.x;
  int l, k, ns0, ns1;
  if (bid < 256){ l = bid>>5; k = bid&31; ns0=0; ns1=l+1; }
  else {
    int q=bid-256; l = 8 + (q>>6); int half=(q>>5)&1; k=q&31;
    int mid=(l+2)>>1;
    ns0 = half? mid : 0; ns1 = half? (l+1) : mid;
  }
  int n=2*l+1;
  __shared__ float d[961];
  __shared__ float2 Xs[8][31];
  __shared__ float2 ph[32];
  int t=threadIdx.x;
  if (t<32) ph[t]=ph32g[t];
  for (int i=t;i<n*n;i+=256) d[i]=dif16[(size_t)(l*32+k)*961+i];
  if (t<8*n){ int b=t/n, mm=t-b*n; Xs[b][mm]=X[b*256+l*l+mm]; }
  __syncthreads();
  int b=t>>5, a=t&31;
  float2* up = u + (size_t)(b*32+k)*4488 + a;
  for (int ns=ns0; ns<ns1; ++ns){
    float ar=0.f, ai=0.f;
    int nn = ns + l;
    for (int mm=0; mm<n; ++mm){
      float2 x=Xs[b][mm];
      float2 p=ph[((mm-l)*a)&31];
      float pr=x.x*p.x-x.y*p.y, pi=x.x*p.y+x.y*p.x;
      float dv=d[mm*n+nn];
      ar += dv*pr; ai += dv*pi;
    }
    up[(size_t)(c_T[l]+ns)*33]=make_float2(ar,ai);
  }
}

// ---------------- big inverse transform v9 + XCD-aware swizzle: the 13 fg-blocks sharing one
// u tile are grouped onto ONE XCD (round-robin xcd = bid&7) so 12/13 u reads become L2 hits.
// rem=(q/13)*8+xcd is bijective: 2496 = 8 XCDs x 24 groups x 13 fg. Math byte-identical to R17.
#define KH_F 8
__global__ __launch_bounds__(512,4) void k_h(const float2* __restrict__ u, const float2* __restrict__ YC,
                                             float* __restrict__ h, double2* __restrict__ part){
  int bid=blockIdx.x;
  int xcd = bid & 7; int q = bid >> 3;
  int fg = q % 13; int rem = (q/13)*8 + xcd;
  int kp = rem & 15; int b = rem >> 4;
  int k0 = kp*2;
  int f0 = fg*KH_F; int F_act = (f0+KH_F<=100)? KH_F : (100-f0);

  __shared__ alignas(16) float2 u2[2][4488];
  __shared__ float2 ysc[KH_F*136];
  int t=threadIdx.x;

  {
    const float4* gs = (const float4*)(u + (size_t)(b*32+k0)*4488);
    float4* ls = (float4*)&u2[0][0];
    for (int j=t; j<4488; j+=512) ls[j]=gs[j];
  }
  for (int i=t; i<KH_F*136; i+=512){
    int fi=i/136, c=i-fi*136;
    float2 y=make_float2(0.f,0.f);
    if (fi<F_act){
      int l=l_from_T(c); int ns=c-c_T[l];
      y=YC[(size_t)(f0+fi)*256 + l*l+l+ns];
    }
    ysc[i]=y;
  }
  __syncthreads();

  int kk = t>>8, tt = t&255;
  float* vbase = (float*)&u2[kk][0];

  {
    int ns = tt>>4; int sub = tt&15; int ft = sub>>3; int at = sub&7;
    int a0 = at*4;
    const float2* uk = u2[kk];
    float ar[16], ai[16];
    #pragma unroll
    for (int q2=0;q2<16;q2++){ ar[q2]=0.f; ai[q2]=0.f; }
    for (int l=ns; l<16; ++l){
      int c = c_T[l]+ns;
      float2 y0=ysc[(ft*4+0)*136+c];
      float2 y1=ysc[(ft*4+1)*136+c];
      float2 y2=ysc[(ft*4+2)*136+c];
      float2 y3=ysc[(ft*4+3)*136+c];
      float2 U0=uk[c*33+a0+0];
      float2 U1=uk[c*33+a0+1];
      float2 U2=uk[c*33+a0+2];
      float2 U3=uk[c*33+a0+3];
      #define CM(j,Y,i_,Ui) \
        ar[(j)*4+(i_)] += (Y).x*(Ui).x - (Y).y*(Ui).y; \
        ai[(j)*4+(i_)] += (Y).x*(Ui).y + (Y).y*(Ui).x;
      CM(0,y0,0,U0) CM(0,y0,1,U1) CM(0,y0,2,U2) CM(0,y0,3,U3)
      CM(1,y1,0,U0) CM(1,y1,1,U1) CM(1,y1,2,U2) CM(1,y1,3,U3)
      CM(2,y2,0,U0) CM(2,y2,1,U1) CM(2,y2,2,U2) CM(2,y2,3,U3)
      CM(3,y3,0,U0) CM(3,y3,1,U1) CM(3,y3,2,U2) CM(3,y3,3,U3)
      #undef CM
    }
    __syncthreads();
    float* vr = vbase;
    float* vi = vbase + 4352;
    #pragma unroll
    for (int j=0;j<4;j++){
      #pragma unroll
      for (int i=0;i<4;i++){
        int fi=ft*4+j, a=a0+i;
        vr[(fi*32+a)*17+ns]=ar[j*4+i];
        vi[(fi*32+a)*17+ns]=ai[j*4+i];
      }
    }
  }
  __syncthreads();

  {
    const float* vr = vbase;
    const float* vi = vbase + 4352;
    int fi=tt>>5, a=tt&31;
    float xr[16], xi[16];
    #pragma unroll
    for (int ns=0;ns<16;ns++){ xr[ns]=vr[(fi*32+a)*17+ns]; xi[ns]=vi[(fi*32+a)*17+ns]; }
    float vr0 = xr[0];
    bool wr = (fi<F_act);
    float* hp = h + ((size_t)(b*100+f0+fi)*32 + (k0+kk))*1024 + a;
    float sf=0.f, qf=0.f;
    #define EMIT(gidx, hv) { float hv_=(hv); if(wr) hp[(gidx)*32]=hv_; sf+=hv_; qf+=hv_*hv_; }
    {
      float se=0.f, so=0.f;
      #pragma unroll
      for (int ns=0; ns<16; ++ns){ if (ns&1) so+=xr[ns]; else se+=xr[ns]; }
      EMIT(0,  2.f*(se+so)-vr0);
      EMIT(16, 2.f*(se-so)-vr0);
    }
    {
      float se=0.f, so=0.f;
      #pragma unroll
      for (int ns=0; ns<16; ++ns){
        const int idx=(ns*8)&31;
        float term = xr[ns]*CS32[idx] - xi[ns]*SN32[idx];
        if (ns&1) so+=term; else se+=term;
      }
      EMIT(8,  2.f*(se+so)-vr0);
      EMIT(24, 2.f*(se-so)-vr0);
    }
    #pragma unroll
    for (int g=1; g<8; ++g){
      float SAe=0.f, SBe=0.f, SAo=0.f, SBo=0.f;
      #pragma unroll
      for (int ns=0; ns<16; ++ns){
        const int idx=(ns*g)&31;
        float A = xr[ns]*CS32[idx];
        float B = xi[ns]*SN32[idx];
        if (ns&1){ SAo+=A; SBo+=B; } else { SAe+=A; SBe+=B; }
      }
      float se1=SAe-SBe, so1=SAo-SBo;
      float se2=SAe+SBe, so2=-(SAo+SBo);
      EMIT(g,      2.f*(se1+so1)-vr0);
      EMIT(g+16,   2.f*(se1-so1)-vr0);
      EMIT(16-g,   2.f*(se2+so2)-vr0);
      EMIT(32-g,   2.f*(se2-so2)-vr0);
    }
    #undef EMIT
    for (int d=16; d>0; d>>=1){ sf += __shfl_down(sf, d, 32); qf += __shfl_down(qf, d, 32); }
    if (a==0 && fi<F_act){
      atomicAdd(&part[b*100+f0+fi].x, (double)sf);
      atomicAdd(&part[b*100+f0+fi].y, (double)qf);
    }
  }
}

// ---------------- BN scale/shift from partials; self-zeroes part ----------------
__global__ void k_bn2(const double2* __restrict__ partial, int per, const float* g, const float* bb,
                      float* scale, float* shift, double2* partial_w){
  int f=blockIdx.x*64+threadIdx.x;
  if (f>=100) return;
  double s=0.0, q=0.0;
  for (int b=0;b<8;b++){ double2 v=partial[b*100+f]; s+=v.x; q+=v.y; }
  for (int b=0;b<8;b++){ partial_w[b*100+f]=make_double2(0.0,0.0); }
  double cnt=8.0*(double)per;
  double mu=s/cnt, var=q/cnt-mu*mu;
  double sc=(double)g[f]/sqrt(var+1e-5);
  scale[f]=(float)sc; shift[f]=(float)((double)bb[f]-mu*sc);
}

// ---------------- k_g v3b: block = (bc, k-quad), 256 thr = 4 waves ----------------
template<int M0>
__device__ __forceinline__ void alpha_dft(const float* __restrict__ yk, float2* __restrict__ tdst, int g){
  float ax0=0.f,ay0=0.f, ax1=0.f,ay1=0.f, ax2=0.f,ay2=0.f, ax3=0.f,ay3=0.f, ax4=0.f,ay4=0.f;
  #pragma unroll
  for (int a=0;a<16;a++){
    float ya=yk[a], yb=yk[a+16];
    float yp=ya+yb, ym=ya-yb;
    #define AM(mi, AX, AY) { \
      const int m_ = M0+mi; \
      const int idx_ = (m_*a)&31; \
      float v_ = (m_&1)? ym : yp; \
      AX += v_*CS32[idx_]; \
      AY -= v_*SN32[idx_]; }
    AM(0,ax0,ay0) AM(1,ax1,ay1) AM(2,ax2,ay2) AM(3,ax3,ay3) AM(4,ax4,ay4)
    #undef AM
  }
  tdst[(M0+0)*33+g]=make_float2(ax0,ay0);
  tdst[(M0+1)*33+g]=make_float2(ax1,ay1);
  tdst[(M0+2)*33+g]=make_float2(ax2,ay2);
  tdst[(M0+3)*33+g]=make_float2(ax3,ay3);
  tdst[(M0+4)*33+g]=make_float2(ax4,ay4);
}

__global__ __launch_bounds__(256) void k_g(const float* __restrict__ h, const float* __restrict__ scale,
                                           const float* __restrict__ shift, const float2* __restrict__ ph32g,
                                           float2* __restrict__ G){
  int bid=blockIdx.x; int kq=bid&7; int bc=bid>>3; int c=bc%100;
  int k0 = kq*4;
  __shared__ float y[4][32*33];
  __shared__ float2 tsc[4][10*33];
  int t=threadIdx.x;
  float sc=scale[c], sh=shift[c];
  {
    const float4* h4 = (const float4*)(h + (size_t)bc*32768 + (size_t)k0*1024);
    for (int i=t;i<1024;i+=256){
      float4 v=h4[i];
      int base=i<<2;
      int kk=base>>10, idx=base&1023, g=idx>>5, a=idx&31;
      float* yw=&y[kk][g*33+a];
      yw[0]=fmaxf(v.x*sc+sh, 0.f);
      yw[1]=fmaxf(v.y*sc+sh, 0.f);
      yw[2]=fmaxf(v.z*sc+sh, 0.f);
      yw[3]=fmaxf(v.w*sc+sh, 0.f);
    }
  }
  __syncthreads();
  int wid=t>>6, lane=t&63;
  {
    int mh=wid&1, kh=wid>>1;
    int kk=kh*2+(lane>>5), g=lane&31;
    const float* yk=&y[kk][g*33];
    if (mh==0) alpha_dft<0>(yk, tsc[kk], g);
    else       alpha_dft<5>(yk, tsc[kk], g);
  }
  __syncthreads();
  if (lane<50){
    int kk=wid;
    int mrow=lane/5, p=lane%5;
    int sa=2*p+1, sb=(p==4)? 0 : 2*p+2;
    const float2* tk=&tsc[kk][mrow*33];
    float2 stA=ph32g[sa];
    float2 stB=ph32g[sb];
    float Aa=0.f,Ba=0.f,Ca=0.f,Da=0.f, Ab=0.f,Bb=0.f,Cb=0.f,Db=0.f;
    #pragma unroll
    for (int half=0; half<2; ++half){
      int ea=(sa*half)&3, eb=(sb*half)&3;
      float2 qa=make_float2(ea==0?1.f:(ea==2?-1.f:0.f), ea==1?1.f:(ea==3?-1.f:0.f));
      float2 qb=make_float2(eb==0?1.f:(eb==2?-1.f:0.f), eb==1?1.f:(eb==3?-1.f:0.f));
      #pragma unroll
      for (int g8=0; g8<8; ++g8){
        int g=half*8+g8;
        float2 ta=tk[g], tb=tk[g+16];
        float tpx=ta.x+tb.x, tpy=ta.y+tb.y;
        float tmx=ta.x-tb.x, tmy=ta.y-tb.y;
        Aa += tmx*qa.x; Ba += tmy*qa.y; Ca += tmy*qa.x; Da += tmx*qa.y;
        Ab += tpx*qb.x; Bb += tpy*qb.y; Cb += tpy*qb.x; Db += tpx*qb.y;
        float nax=qa.x*stA.x - qa.y*stA.y, nay=qa.x*stA.y + qa.y*stA.x; qa=make_float2(nax,nay);
        float nbx=qb.x*stB.x - qb.y*stB.y, nby=qb.x*stB.y + qb.y*stB.x; qb=make_float2(nbx,nby);
      }
    }
    float2* Gp = G + (size_t)(bc*32 + k0+kk)*190 + mrow*19;
    Gp[9+sa]=make_float2(Aa+Ba, Ca-Da);
    Gp[9-sa]=make_float2(Aa-Ba, Ca+Da);
    Gp[9+sb]=make_float2(Ab+Bb, Cb-Db);
    Gp[9-sb]=make_float2(Ab-Bb, Cb+Db);
  }
}

// ---------------- k_x2 (proven flat): X2h = sum_k wd16 * G ----------------
__global__ void k_x2(const float2* __restrict__ G, const float* __restrict__ wd16, float2* __restrict__ X2){
  int tid=blockIdx.x*256+threadIdx.x;
  if (tid>=800*715) return;
  int bc=tid/715, i=tid-bc*715;
  int l=l_from_offH(i); int rem=i-c_offH[l]; int n=2*l+1;
  int m=rem/n, kk2=rem-m*n; int ng=kk2-l;
  int j = m*19+(ng+9);
  const float2* Gp = G + (size_t)bc*32*190 + j;
  const float*  wp = wd16 + (size_t)l*32*361 + (m+l)*n + kk2;
  float ar=0.f, ai=0.f;
  #pragma unroll 8
  for (int k=0;k<32;k++){
    float2 gv=Gp[(size_t)k*190];
    float  wv=wp[(size_t)k*361];
    ar += wv*gv.x; ai += wv*gv.y;
  }
  X2[tid]=make_float2(ar, ai);
}

// ---------------- k_A (proven flat): 2-way unrolled complex dot over kk ----------------
__global__ void k_A(const float2* __restrict__ X2, const float* __restrict__ Df, float2* __restrict__ A){
  int tid = blockIdx.x*256 + threadIdx.x;
  if (tid >= 800*715) return;
  int bi = tid/715, off = tid - bi*715;
  int l = l_from_offH(off); int rem = off - c_offH[l]; int n = 2*l+1;
  int m = rem/n, nn = rem - m*n;
  const float2* Xp = X2 + (size_t)bi*715 + c_offH[l] + m*n;
  const float* Dp = Df + l*961 + nn*n;
  float ar=0.f, ai=0.f;
  float br=0.f, bis=0.f;
  int kk=0;
  for (; kk+1<n; kk+=2){
    float2 x0 = Xp[kk];   float d0 = Dp[kk];
    float2 x1 = Xp[kk+1]; float d1 = Dp[kk+1];
    ar += x0.x*d0; ai += x0.y*d0;
    br += x1.x*d1; bis += x1.y*d1;
  }
  if (kk<n){ float2 x = Xp[kk]; float dv = Dp[kk]; ar += x.x*dv; ai += x.y*dv; }
  A[tid] = make_float2(ar+br, ai+bis);
}

// ---------------- Z2 (half rows): Z2h = sum_i A * conj(What2) ----------------
__global__ void k_z2(const float2* A, const float2* WH2, float2* Z2){
  int bid=blockIdx.x; int b=bid&7; int r=bid>>3;
  int l=l_from_sq(r); int nn=r-l*l; int n=2*l+1; int ns=nn-l;
  int nrow=l+1;
  __shared__ float2 As[100*10];
  int t=threadIdx.x;
  for (int idx=t; idx<100*nrow; idx+=256){
    int i=idx/nrow, m=idx-i*nrow;
    As[idx]=A[(size_t)(b*100+i)*715 + c_offH[l] + m*n + nn];
  }
  __syncthreads();
  int mabs = ns<0?-ns:ns;
  const float2* Wp = WH2 + (size_t)mabs*10000;
  float sgn = (ns>=0)? -1.f : 1.f;
  for (int idx=t; idx<100*nrow; idx+=256){
    int o=idx/nrow, m=idx-o*nrow;
    float zr=0.f, zi=0.f;
    #pragma unroll 4
    for (int i=0;i<100;i++){
      float2 a=As[i*nrow+m];
      float2 w=Wp[i*100+o]; float wr=w.x, wi=sgn*w.y;
      zr += a.x*wr - a.y*wi;
      zi += a.x*wi + a.y*wr;
    }
    Z2[(size_t)(b*100+o)*715 + c_offH[l] + m*n + nn]=make_float2(zr,zi);
  }
}

// ---------------- fused SO3 IFFT at b=10 v6 + XCD swizzle: 10 kp-blocks sharing Zs[bf]
// grouped onto one XCD (8000 = 8 x 100 x 10, bijective). Math byte-identical.
__global__ __launch_bounds__(256) void k_ifft10(const float2* __restrict__ Z2, const float* __restrict__ dif10t,
                                                const float2* __restrict__ ph20g, float* __restrict__ h2,
                                                double2* __restrict__ part){
  int bid=blockIdx.x;
  int xcd = bid & 7; int q = bid >> 3;
  int kp = q % 10; int bf = (q/10)*8 + xcd;
  int k0=kp*2;
  __shared__ float2 Zs[715];
  __shared__ float2 M[2][190];
  __shared__ float2 T[2][200];
  __shared__ float2 ph[20];
  __shared__ float rs[256], rq[256];
  int t=threadIdx.x;
  if (t<20) ph[t]=ph20g[t];
  const float2* Zp = Z2 + (size_t)bf*715;
  for (int i=t;i<715;i+=256) Zs[i]=Zp[i];
  __syncthreads();
  {
    int kk = t>>7, tt = t&127;
    int k = k0+kk;
    for (int i=tt;i<190;i+=128){
      int ms=i/19, n9=i-ms*19; int nsg=n9-9;
      int a2=nsg<0?-nsg:nsg; int l0 = ms>a2?ms:a2;
      float mr=0.f, mi=0.f;
      const float* dp = dif10t + (size_t)k*1900 + i;
      for (int l=l0;l<10;l++){
        float dv=dp[l*190];
        float2 z=Zs[c_offH[l] + ms*(2*l+1) + nsg + l];
        mr += dv*z.x; mi += dv*z.y;
      }
      M[kk][i]=make_float2(mr,mi);
    }
  }
  __syncthreads();
  if (t<200){
    int kk=t/100, j=t-100*kk;
    int g=j/5, ms0=(j%5)*2;
    const float2* Mp0=&M[kk][ms0*19];
    const float2* Mp1=Mp0+19;
    float2 stp=ph[g];
    float2 p=ph[(11*g)%20];
    float tr0=0.f,ti0=0.f,tr1=0.f,ti1=0.f;
    #pragma unroll
    for (int n9=0;n9<19;n9++){
      float2 m0=Mp0[n9], m1=Mp1[n9];
      tr0 += m0.x*p.x - m0.y*p.y;
      ti0 += m0.x*p.y + m0.y*p.x;
      tr1 += m1.x*p.x - m1.y*p.y;
      ti1 += m1.x*p.y + m1.y*p.x;
      float nx=p.x*stp.x - p.y*stp.y, ny=p.x*stp.y + p.y*stp.x;
      p=make_float2(nx,ny);
    }
    T[kk][ms0*20+g]=make_float2(tr0,ti0);
    T[kk][(ms0+1)*20+g]=make_float2(tr1,ti1);
  }
  __syncthreads();
  float sf=0.f, qf=0.f;
  if (t<200){
    int kk=t/100, j=t-100*kk;
    int a=j/5, g0=(j%5)*4;
    const float2* Tk=&T[kk][0];
    float acc0=Tk[g0].x, acc1=Tk[g0+1].x, acc2=Tk[g0+2].x, acc3=Tk[g0+3].x;
    float2 stp=ph[a];
    float2 p=stp;
    #pragma unroll
    for (int ms=1; ms<10; ++ms){
      const float2* Tp=&Tk[ms*20+g0];
      float2 t0=Tp[0], t1=Tp[1], t2=Tp[2], t3=Tp[3];
      acc0 += 2.f*(t0.x*p.x - t0.y*p.y);
      acc1 += 2.f*(t1.x*p.x - t1.y*p.y);
      acc2 += 2.f*(t2.x*p.x - t2.y*p.y);
      acc3 += 2.f*(t3.x*p.x - t3.y*p.y);
      float nx=p.x*stp.x - p.y*stp.y, ny=p.x*stp.y + p.y*stp.x;
      p=make_float2(nx,ny);
    }
    float* hp = h2 + (size_t)bf*8000 + (k0+kk)*400 + a*20 + g0;
    *(float4*)hp = make_float4(acc0,acc1,acc2,acc3);
    sf = acc0+acc1+acc2+acc3;
    qf = acc0*acc0+acc1*acc1+acc2*acc2+acc3*acc3;
  }
  rs[t]=sf; rq[t]=qf; __syncthreads();
  for (int w=128;w>0;w>>=1){ if(t<w){rs[t]+=rs[t+w]; rq[t]+=rq[t+w];} __syncthreads(); }
  if (t==0){
    atomicAdd(&part[bf].x, (double)rs[0]);
    atomicAdd(&part[bf].y, (double)rq[0]);
  }
}

// ---------------- BN2+ReLU + SO3 integrate -> feat ----------------
__global__ void k_integrate(const float* h2, const float* scale, const float* shift, const float* qw10, float* feat){
  int bf=blockIdx.x; int f=bf%100; int t=threadIdx.x;
  float sc=scale[f], sh=shift[f];
  const float4* p4=(const float4*)(h2+(size_t)bf*8000);
  float s=0.f;
  for (int i4=t;i4<2000;i4+=256){
    float4 v=p4[i4];
    float qw=qw10[i4/100];
    float r0=fmaxf(v.x*sc+sh,0.f);
    float r1=fmaxf(v.y*sc+sh,0.f);
    float r2=fmaxf(v.z*sc+sh,0.f);
    float r3=fmaxf(v.w*sc+sh,0.f);
    s += (r0+r1+r2+r3)*qw;
  }
  __shared__ float r[256];
  r[t]=s; __syncthreads();
  for (int w=128;w>0;w>>=1){ if(t<w) r[t]+=r[t+w]; __syncthreads(); }
  if (t==0){
    float c=(float)((2.0*M_PI/20.0)*(2.0*M_PI/20.0));
    feat[bf]=r[0]*c;
  }
}

// ---------------- final linear ----------------
__global__ void k_logits(const float* feat, const float* lw, const float* lb, float* out){
  int t=blockIdx.x*64+threadIdx.x;
  if (t>=320) return;
  int b=t/40, c=t-40*b;
  float s=lb[c];
  for (int f=0;f<100;f++) s += feat[b*100+f]*lw[f*40+c];
  out[t]=s;
}

extern "C" void kernel_launch(void* const* d_in, const int* in_sizes, int n_in,
                              void* d_out, int out_size, void* d_ws, size_t ws_size,
                              hipStream_t stream){
  (void)in_sizes; (void)n_in; (void)out_size; (void)ws_size;
  const float* x    = (const float*)d_in[0];
  const float* w_s2 = (const float*)d_in[1];
  const float* bn1g = (const float*)d_in[3];
  const float* bn1b = (const float*)d_in[4];
  const float* w_so3= (const float*)d_in[5];
  const float* bn2g = (const float*)d_in[7];
  const float* bn2b = (const float*)d_in[8];
  const float* linw = (const float*)d_in[9];
  const float* linb = (const float*)d_in[10];
  float* out = (float*)d_out;

  char* base=(char*)d_ws; size_t off=0;
  auto alloc=[&](size_t bytes)->void*{ void* p=base+off; off=(off+bytes+255)&~(size_t)255; return p; };
  double* Dd   = (double*)alloc((size_t)16*961*8);
  float*  Df   = (float*) alloc((size_t)16*961*4);
  float*  qw30 = (float*) alloc(256);
  float*  qw16 = (float*) alloc(256);
  float*  qw10 = (float*) alloc(256);
  float2* ph60 = (float2*)alloc(512);
  float2* ph32 = (float2*)alloc(256);
  float2* ph20 = (float2*)alloc(256);
  float*  wd_s2= (float*) alloc((size_t)16*60*31*4);
  float*  dif16= (float*) alloc((size_t)16*32*961*4);
  float*  wd16 = (float*) alloc((size_t)10*32*361*4);
  float*  dif10t=(float*) alloc((size_t)20*10*190*4);
  float*  img  = (float*) alloc((size_t)8*3600*4);
  float2* X    = (float2*)alloc((size_t)8*256*8);
  float2* YC   = (float2*)alloc((size_t)100*256*8);
  float2* u    = (float2*)alloc((size_t)8*32*4488*8);
  float*  h    = (float*) alloc((size_t)8*100*32768*4);
  float*  sc1  = (float*) alloc(512);
  float*  sh1  = (float*) alloc(512);
  float2* Gbuf = (float2*)alloc((size_t)800*32*190*8);
  float2* X2   = (float2*)alloc((size_t)800*715*8);
  float2* WH2  = (float2*)alloc((size_t)10*100*100*8);
  float2* A    = (float2*)alloc((size_t)800*715*8);
  float2* Z2   = (float2*)alloc((size_t)800*715*8);
  float*  h2   = (float*) alloc((size_t)8*100*8000*4);
  float*  sc2  = (float*) alloc(512);
  float*  sh2  = (float*) alloc(512);
  float*  feat = (float*) alloc(4096);
  double2* part= (double2*)alloc((size_t)800*16);
  unsigned long long* tflag = (unsigned long long*)alloc(256);

  k_dq<<<17, 1024, 0, stream>>>(Dd, Df, qw30, qw16, qw10, ph32, ph20, ph60, tflag);
  k_tables<<<1672, 256, 0, stream>>>(Dd, qw30, qw16, qw10, wd_s2, dif16, wd16, dif10t, tflag);
  k_prep<<<32, 256, 0, stream>>>(tflag, img, part);
  k_project<<<32, 256, 0, stream>>>(x, img);
  k_front<<<148, 256, 0, stream>>>(img, ph60, wd_s2, X, w_s2, Df, YC, w_so3, ph32, WH2);
  k_u<<<768, 256, 0, stream>>>(X, dif16, ph32, u);
  k_h<<<8*16*13, 512, 0, stream>>>(u, YC, h, part);
  k_bn2<<<2, 64, 0, stream>>>(part, 32768, bn1g, bn1b, sc1, sh1, part);
  k_g<<<800*8, 256, 0, stream>>>(h, sc1, sh1, ph32, Gbuf);
  k_x2<<<(800*715+255)/256, 256, 0, stream>>>(Gbuf, wd16, X2);
  k_A<<<(800*715+255)/256, 256, 0, stream>>>(X2, Df, A);
  k_z2<<<800, 256, 0, stream>>>(A, WH2, Z2);
  k_ifft10<<<8000, 256, 0, stream>>>(Z2, dif10t, ph20, h2, part);
  k_bn2<<<2, 64, 0, stream>>>(part, 8000, bn2g, bn2b, sc2, sh2, part);
  k_integrate<<<800, 256, 0, stream>>>(h2, sc2, sh2, qw10, feat);
  k_logits<<<5, 64, 0, stream>>>(feat, linw, linb, out);
}